// Round 8
// baseline (403.078 us; speedup 1.0000x reference)
//
#include <hip/hip_runtime.h>
#include <hip/hip_bf16.h>
#include <math.h>

#define B_  2
#define S_  2048
#define H_  1024
#define NH_ 4
#define DH_ 256

typedef __attribute__((ext_vector_type(8))) short short8;
typedef __attribute__((ext_vector_type(2))) short short2v;
typedef __attribute__((ext_vector_type(4))) float f32x4;

static __device__ __forceinline__ short f2bf(float x) {
  __hip_bfloat16 h = __float2bfloat16(x);
  union { __hip_bfloat16 h; short s; } u;
  u.h = h;
  return u.s;
}

static __device__ __forceinline__ short8 pack8(const float4& a, const float4& b) {
  short8 t;
  t[0] = f2bf(a.x); t[1] = f2bf(a.y); t[2] = f2bf(a.z); t[3] = f2bf(a.w);
  t[4] = f2bf(b.x); t[5] = f2bf(b.y); t[6] = f2bf(b.z); t[7] = f2bf(b.w);
  return t;
}

// ---------------------------------------------------------------------------
// Kernel 1: gate projections (float4 h-vectorized).
// ---------------------------------------------------------------------------
__global__ __launch_bounds__(256) void gates_kernel(
    const float* __restrict__ q, const float* __restrict__ k,
    const float* __restrict__ v,
    const float* __restrict__ igk, const float* __restrict__ igb,
    const float* __restrict__ fgk, const float* __restrict__ fgb,
    float* __restrict__ ig_pre, float* __restrict__ lsf) {
  int bs = blockIdx.x;
  int b = bs / S_, s = bs % S_;
  const float* qrow = q + ((size_t)b * S_ + s) * H_;
  const float* krow = k + ((size_t)b * S_ + s) * H_;
  const float* vrow = v + ((size_t)b * S_ + s) * H_;

  int h0 = threadIdx.x * 4;  // H_=1024 = 256*4, exactly one float4 per thread
  float4 q4 = *reinterpret_cast<const float4*>(qrow + h0);
  float4 k4 = *reinterpret_cast<const float4*>(krow + h0);
  float4 v4 = *reinterpret_cast<const float4*>(vrow + h0);
  float qv[4] = {q4.x, q4.y, q4.z, q4.w};
  float kv[4] = {k4.x, k4.y, k4.z, k4.w};
  float vv[4] = {v4.x, v4.y, v4.z, v4.w};

  const float4* igk4 = reinterpret_cast<const float4*>(igk);  // row-major (3H,4)
  const float4* fgk4 = reinterpret_cast<const float4*>(fgk);

  float accI[NH_] = {0.f, 0.f, 0.f, 0.f};
  float accF[NH_] = {0.f, 0.f, 0.f, 0.f};
#pragma unroll
  for (int e = 0; e < 4; ++e) {
    int h = h0 + e;
    float4 wiq = igk4[h], wik = igk4[H_ + h], wiv = igk4[2 * H_ + h];
    float4 wfq = fgk4[h], wfk = fgk4[H_ + h], wfv = fgk4[2 * H_ + h];
    accI[0] += qv[e] * wiq.x + kv[e] * wik.x + vv[e] * wiv.x;
    accI[1] += qv[e] * wiq.y + kv[e] * wik.y + vv[e] * wiv.y;
    accI[2] += qv[e] * wiq.z + kv[e] * wik.z + vv[e] * wiv.z;
    accI[3] += qv[e] * wiq.w + kv[e] * wik.w + vv[e] * wiv.w;
    accF[0] += qv[e] * wfq.x + kv[e] * wfk.x + vv[e] * wfv.x;
    accF[1] += qv[e] * wfq.y + kv[e] * wfk.y + vv[e] * wfv.y;
    accF[2] += qv[e] * wfq.z + kv[e] * wfk.z + vv[e] * wfv.z;
    accF[3] += qv[e] * wfq.w + kv[e] * wfk.w + vv[e] * wfv.w;
  }
#pragma unroll
  for (int n = 0; n < NH_; ++n) {
    for (int m = 1; m < 64; m <<= 1) {
      accI[n] += __shfl_xor(accI[n], m);
      accF[n] += __shfl_xor(accF[n], m);
    }
  }
  __shared__ float red[4][8];
  int wave = threadIdx.x >> 6;
  int lane = threadIdx.x & 63;
  if (lane == 0) {
#pragma unroll
    for (int n = 0; n < NH_; ++n) {
      red[wave][n] = accI[n];
      red[wave][4 + n] = accF[n];
    }
  }
  __syncthreads();
  if (threadIdx.x < 8) {
    int t = threadIdx.x;
    float sum = red[0][t] + red[1][t] + red[2][t] + red[3][t];
    if (t < 4) {
      int n = t;
      ig_pre[((size_t)(b * NH_ + n)) * S_ + s] = sum + igb[n];
    } else {
      int n = t - 4;
      float x = sum + fgb[n];
      float ls = (x >= 0.f) ? -log1pf(expf(-x)) : (x - log1pf(expf(x)));
      lsf[((size_t)(b * NH_ + n)) * S_ + s] = ls;
    }
  }
}

// ---------------------------------------------------------------------------
// Kernel 2: per-(b,nh) scan — in-register version (proven rounds 6/7).
// ---------------------------------------------------------------------------
__global__ __launch_bounds__(64) void scan_kernel(
    const float* __restrict__ ig_pre, const float* __restrict__ lsf,
    float* __restrict__ a_out, float* __restrict__ M_out,
    float* __restrict__ fl_out) {
  int hd = blockIdx.x;
  int lane = threadIdx.x;
  const float* ig = ig_pre + (size_t)hd * S_;
  const float* ls = lsf + (size_t)hd * S_;
  float xs[32], ys[32];
#pragma unroll
  for (int c = 0; c < 32; ++c) xs[c] = ls[c * 64 + lane];
#pragma unroll
  for (int c = 0; c < 32; ++c) ys[c] = ig[c * 64 + lane];

  float carry = 0.f;
  float mcarry = -INFINITY;
#pragma unroll
  for (int c = 0; c < 32; ++c) {
    int s = c * 64 + lane;
    float x = xs[c];
    for (int off = 1; off < 64; off <<= 1) {
      float t = __shfl_up(x, off);
      if (lane >= off) x += t;
    }
    float csum = carry + x;
    float a = ys[c] - csum;
    float y = a;
    for (int off = 1; off < 64; off <<= 1) {
      float t = __shfl_up(y, off);
      if (lane >= off) y = fmaxf(y, t);
    }
    float M = fmaxf(mcarry, y);
    a_out[(size_t)hd * S_ + s] = a;
    M_out[(size_t)hd * S_ + s] = M;
    fl_out[(size_t)hd * S_ + s] = expf(-(csum + M));
    carry = __shfl(csum, 63);
    mcarry = __shfl(M, 63);
  }
}

// ---------------------------------------------------------------------------
// Kernel 3: MFMA main kernel, 4-way j-split + 4 blocks/CU.
//   grid = 1024: bid = p*256 + idx; hd = idx&7 (XCD-affine head),
//   s = idx>>3 (CU slot), rtb = (p even) ? 31-s : s  (complement pairing so a
//   CU's 4 blocks are ~balanced: two long (~16 iters) + two short).
//   Block does j-tiles jt = p, p+4, ... <= 2*rtb+1  (<=16 iterations).
//   All parities atomicAdd partial O into po[] and rowsum into rsb[]
//   (zeroed by hipMemsetAsync each launch; ULP-level atomic reorder only).
// LDS (single V buffer, stride 36):
//   K  [0,16384):        [32 j][256 d] bf16, 16B slots, phys = slot^(j&7)
//   vT [16384,34816):    elem(d,j) at short d*36 + (j^(((d>>4)&3)<<3))
//   P  [34816,39936):    per-wave [16][40] shorts
//   39936 B/block -> 4 blocks/CU (159744 <= 160K); launch_bounds(256,4).
// ---------------------------------------------------------------------------
#define VSTR 36
#define KOFF 0
#define VOFF 16384
#define POFF (16384 + 2 * VSTR * 256)
#define SMEM_BYTES (POFF + 4 * 1280)

__global__ __launch_bounds__(256, 4) void mlstm_mfma(
    const float* __restrict__ q, const float* __restrict__ k,
    const float* __restrict__ v,
    const float* __restrict__ a_arr, const float* __restrict__ M_arr,
    float* __restrict__ po, float* __restrict__ rsb) {
  __shared__ __align__(16) char smem[SMEM_BYTES];

  const int bid = blockIdx.x;
  const int p = bid >> 8;
  const int idx = bid & 255;
  const int hd = idx & 7;
  const int cs = idx >> 3;                 // CU slot within XCD stream
  const int rtb = (p & 1) ? cs : 31 - cs;  // complement pairing
  const int lim = 2 * rtb + 1;
  const int ntiles = (p <= lim) ? ((lim - p) >> 2) + 1 : 0;
  if (ntiles <= 0) return;

  const int b = hd >> 2, nh = hd & 3;
  const int i0 = rtb * 64;

  const int tid = threadIdx.x;
  const int wave = tid >> 6;
  const int l = tid & 63;
  const int g = l >> 4;      // 0..3
  const int c16 = l & 15;    // 0..15
  const int iw = i0 + wave * 16;

  const short8* kb8 = reinterpret_cast<const short8*>(smem + KOFF);
  short* vt = reinterpret_cast<short*>(smem + VOFF);
  short* pb = reinterpret_cast<short*>(smem + POFF + wave * 1280);

  // ---- Q A-fragments: row = iw + c16, k-elems = 32c + 8g + e ----
  short8 qf[8];
  {
    const float* qp = q + ((size_t)b * S_ + (iw + c16)) * H_ + nh * DH_;
#pragma unroll
    for (int c = 0; c < 8; ++c) {
      int d0 = c * 32 + g * 8;
      float4 f0 = *reinterpret_cast<const float4*>(qp + d0);
      float4 f1 = *reinterpret_cast<const float4*>(qp + d0 + 4);
      qf[c] = pack8(f0, f1);
    }
  }
  float Mr[4];
#pragma unroll
  for (int r = 0; r < 4; ++r)
    Mr[r] = M_arr[(size_t)hd * S_ + iw + 4 * g + r];

  f32x4 oa[16];
#pragma unroll
  for (int d = 0; d < 16; ++d) oa[d] = (f32x4){0.f, 0.f, 0.f, 0.f};
  float rs[4] = {0.f, 0.f, 0.f, 0.f};

  // staging maps
  const int sjk = tid >> 3;   // K row 0..31
  const int sck = tid & 7;    // K d-block of 32
  const int sjp = tid >> 4;   // V row-pair 0..15
  const int scv = tid & 15;   // V d-stripe base

  const float* kgb = k + (size_t)b * S_ * H_ + nh * DH_;
  const float* vgb = v + (size_t)b * S_ * H_ + nh * DH_;
  const float* agb = a_arr + (size_t)hd * S_;

  const int jtmaxW = (iw + 15) >> 5;  // causal cap per wave

  for (int n = 0; n < ntiles; ++n) {
    const int jt = p + 4 * n;
    const bool active = (jt <= jtmaxW);

    // ---- stage K (interleaved load/pack/write, short reg lifetimes) ----
    {
      const float* kp = kgb + (size_t)(jt * 32 + sjk) * H_ + sck * 32;
      short8* krow8 = const_cast<short8*>(kb8) + sjk * 32;
#pragma unroll
      for (int u = 0; u < 4; ++u) {
        float4 a0 = *reinterpret_cast<const float4*>(kp + 8 * u);
        float4 a1 = *reinterpret_cast<const float4*>(kp + 8 * u + 4);
        int phys = (4 * sck + u) ^ (sjk & 7);
        krow8[phys] = pack8(a0, a1);
      }
    }
    // ---- stage V transposed ----
    {
      const float* vp0 = vgb + (size_t)(jt * 32 + 2 * sjp) * H_;
      const float* vp1 = vp0 + H_;
#pragma unroll
      for (int m = 0; m < 16; ++m) {
        int d = scv + 16 * m;
        int jph = (2 * sjp) ^ ((m & 3) << 3);
        short2v t;
        t[0] = f2bf(vp0[scv + 16 * m]);
        t[1] = f2bf(vp1[scv + 16 * m]);
        *reinterpret_cast<short2v*>(vt + d * VSTR + jph) = t;
      }
    }
    __syncthreads();  // staging visible to all waves

    if (active) {
      const int j0 = jt * 32;
      // ---- S = Q K^T (two 16-wide j sub-tiles) ----
      f32x4 sa0 = {0.f, 0.f, 0.f, 0.f}, sa1 = {0.f, 0.f, 0.f, 0.f};
#pragma unroll
      for (int c = 0; c < 8; ++c) {
        int row0 = c16, row1 = 16 + c16;
        int slot = 4 * c + g;
        short8 kf0 = kb8[row0 * 32 + (slot ^ (row0 & 7))];
        short8 kf1 = kb8[row1 * 32 + (slot ^ (row1 & 7))];
        sa0 = __builtin_amdgcn_mfma_f32_16x16x32_bf16(qf[c], kf0, sa0, 0, 0, 0);
        sa1 = __builtin_amdgcn_mfma_f32_16x16x32_bf16(qf[c], kf1, sa1, 0, 0, 0);
      }
      // ---- weights, causal mask, rowsum, P -> wave-private LDS ----
      float a0 = agb[j0 + c16];
      float a1 = agb[j0 + 16 + c16];
#pragma unroll
      for (int r = 0; r < 4; ++r) {
        int i = iw + 4 * g + r;
        float w0 = sa0[r] * 0.0625f * __expf(a0 - Mr[r]);
        if (j0 + c16 > i) w0 = 0.f;
        float w1 = sa1[r] * 0.0625f * __expf(a1 - Mr[r]);
        if (j0 + 16 + c16 > i) w1 = 0.f;
        rs[r] += w0 + w1;
        pb[(4 * g + r) * 40 + c16]      = f2bf(w0);
        pb[(4 * g + r) * 40 + 16 + c16] = f2bf(w1);
      }
      asm volatile("" ::: "memory");  // order P write before P read (same wave)
      short8 pa = *reinterpret_cast<const short8*>(pb + c16 * 40 + 8 * g);
      // ---- O += P V ----
#pragma unroll
      for (int dq = 0; dq < 16; ++dq) {
        short8 vf = *reinterpret_cast<const short8*>(
            vt + (16 * dq + c16) * VSTR + 8 * (g ^ (dq & 3)));
        oa[dq] = __builtin_amdgcn_mfma_f32_16x16x32_bf16(pa, vf, oa[dq], 0, 0, 0);
      }
    }
    __syncthreads();  // all waves done reading before next staging overwrite
  }

  // ---- rowsum reduce across the 16-lane group, then atomic accumulate ----
#pragma unroll
  for (int r = 0; r < 4; ++r) {
    rs[r] += __shfl_xor(rs[r], 1);
    rs[r] += __shfl_xor(rs[r], 2);
    rs[r] += __shfl_xor(rs[r], 4);
    rs[r] += __shfl_xor(rs[r], 8);
  }
  if (c16 == 0) {
#pragma unroll
    for (int r = 0; r < 4; ++r)
      atomicAdd(&rsb[hd * S_ + iw + 4 * g + r], rs[r]);
  }
#pragma unroll
  for (int dq = 0; dq < 16; ++dq)
#pragma unroll
    for (int r = 0; r < 4; ++r)
      atomicAdd(&po[((size_t)(hd * S_ + iw + 4 * g + r)) * DH_ + dq * 16 + c16],
                oa[dq][r]);
}

// ---------------------------------------------------------------------------
// Kernel 4: combine partials -> normalizer + multihead layernorm -> out.
//   1 wave per row (4 waves/block, grid 4096). Lane owns 4 consecutive d.
// ---------------------------------------------------------------------------
__global__ __launch_bounds__(256) void combine_kernel(
    const float* __restrict__ po, const float* __restrict__ rsb,
    const float* __restrict__ fl_arr, const float* __restrict__ scale,
    float* __restrict__ out) {
  int ridx = blockIdx.x * 4 + (threadIdx.x >> 6);
  int lane = threadIdx.x & 63;
  int hd = ridx >> 11, i = ridx & 2047;
  int b = hd >> 2, nh = hd & 3;

  float4 a4 = *reinterpret_cast<const float4*>(
      po + ((size_t)(hd * S_ + i)) * DH_ + lane * 4);

  float rsum = rsb[hd * S_ + i];
  float fl = fl_arr[(size_t)hd * S_ + i];
  float inv = 1.f / (fmaxf(fabsf(rsum), fl) + 1e-6f);

  float o0 = a4.x * inv;
  float o1 = a4.y * inv;
  float o2 = a4.z * inv;
  float o3 = a4.w * inv;

  float s1 = o0 + o1 + o2 + o3;
  float s2 = o0 * o0 + o1 * o1 + o2 * o2 + o3 * o3;
#pragma unroll
  for (int m = 1; m < 64; m <<= 1) {
    s1 += __shfl_xor(s1, m);
    s2 += __shfl_xor(s2, m);
  }
  float mean = s1 * (1.f / DH_);
  float var = s2 * (1.f / DH_) - mean * mean;
  float rstd = rsqrtf(var + 1e-6f);

  const float* scp = scale + nh * DH_ + lane * 4;
  float4 res;
  res.x = (o0 - mean) * rstd * scp[0];
  res.y = (o1 - mean) * rstd * scp[1];
  res.z = (o2 - mean) * rstd * scp[2];
  res.w = (o3 - mean) * rstd * scp[3];
  float* op = out + ((size_t)b * S_ + i) * H_ + nh * DH_ + lane * 4;
  *reinterpret_cast<float4*>(op) = res;
}

// ---------------------------------------------------------------------------
extern "C" void kernel_launch(void* const* d_in, const int* in_sizes, int n_in,
                              void* d_out, int out_size, void* d_ws,
                              size_t ws_size, hipStream_t stream) {
  const float* q   = (const float*)d_in[0];
  const float* k   = (const float*)d_in[1];
  const float* v   = (const float*)d_in[2];
  const float* igk = (const float*)d_in[3];
  const float* igb = (const float*)d_in[4];
  const float* fgk = (const float*)d_in[5];
  const float* fgb = (const float*)d_in[6];
  const float* scl = (const float*)d_in[7];
  float* out = (float*)d_out;

  const size_t seq = (size_t)B_ * NH_ * S_;  // 16384
  float* ws = (float*)d_ws;
  float* ig_pre = ws;
  float* lsf    = ws + seq;
  float* a_arr  = ws + 2 * seq;
  float* M_arr  = ws + 3 * seq;
  float* fl_arr = ws + 4 * seq;
  float* rsb    = ws + 5 * seq;
  float* po     = ws + 6 * seq;   // 8*2048*256 floats = 16.8 MB

  hipMemsetAsync(po, 0, (size_t)8 * 2048 * 256 * 4, stream);
  hipMemsetAsync(rsb, 0, seq * 4, stream);
  gates_kernel<<<B_ * S_, 256, 0, stream>>>(q, k, v, igk, igb, fgk, fgb,
                                            ig_pre, lsf);
  scan_kernel<<<B_ * NH_, 64, 0, stream>>>(ig_pre, lsf, a_arr, M_arr, fl_arr);
  mlstm_mfma<<<1024, 256, 0, stream>>>(q, k, v, a_arr, M_arr, po, rsb);
  combine_kernel<<<B_ * NH_ * S_ / 4, 256, 0, stream>>>(
      po, rsb, fl_arr, scl, out);
}

// Round 9
// 320.396 us; speedup vs baseline: 1.2581x; 1.2581x over previous
//
#include <hip/hip_runtime.h>
#include <hip/hip_bf16.h>
#include <math.h>

#define B_  2
#define S_  2048
#define H_  1024
#define NH_ 4
#define DH_ 256

typedef __attribute__((ext_vector_type(8))) short short8;
typedef __attribute__((ext_vector_type(2))) short short2v;
typedef __attribute__((ext_vector_type(4))) float f32x4;

static __device__ __forceinline__ short f2bf(float x) {
  __hip_bfloat16 h = __float2bfloat16(x);
  union { __hip_bfloat16 h; short s; } u;
  u.h = h;
  return u.s;
}

static __device__ __forceinline__ short8 pack8(const float4& a, const float4& b) {
  short8 t;
  t[0] = f2bf(a.x); t[1] = f2bf(a.y); t[2] = f2bf(a.z); t[3] = f2bf(a.w);
  t[4] = f2bf(b.x); t[5] = f2bf(b.y); t[6] = f2bf(b.z); t[7] = f2bf(b.w);
  return t;
}

// ---------------------------------------------------------------------------
// Kernel 1: gate projections (float4 h-vectorized, proven round 8).
// ---------------------------------------------------------------------------
__global__ __launch_bounds__(256) void gates_kernel(
    const float* __restrict__ q, const float* __restrict__ k,
    const float* __restrict__ v,
    const float* __restrict__ igk, const float* __restrict__ igb,
    const float* __restrict__ fgk, const float* __restrict__ fgb,
    float* __restrict__ ig_pre, float* __restrict__ lsf) {
  int bs = blockIdx.x;
  int b = bs / S_, s = bs % S_;
  const float* qrow = q + ((size_t)b * S_ + s) * H_;
  const float* krow = k + ((size_t)b * S_ + s) * H_;
  const float* vrow = v + ((size_t)b * S_ + s) * H_;

  int h0 = threadIdx.x * 4;
  float4 q4 = *reinterpret_cast<const float4*>(qrow + h0);
  float4 k4 = *reinterpret_cast<const float4*>(krow + h0);
  float4 v4 = *reinterpret_cast<const float4*>(vrow + h0);
  float qv[4] = {q4.x, q4.y, q4.z, q4.w};
  float kv[4] = {k4.x, k4.y, k4.z, k4.w};
  float vv[4] = {v4.x, v4.y, v4.z, v4.w};

  const float4* igk4 = reinterpret_cast<const float4*>(igk);
  const float4* fgk4 = reinterpret_cast<const float4*>(fgk);

  float accI[NH_] = {0.f, 0.f, 0.f, 0.f};
  float accF[NH_] = {0.f, 0.f, 0.f, 0.f};
#pragma unroll
  for (int e = 0; e < 4; ++e) {
    int h = h0 + e;
    float4 wiq = igk4[h], wik = igk4[H_ + h], wiv = igk4[2 * H_ + h];
    float4 wfq = fgk4[h], wfk = fgk4[H_ + h], wfv = fgk4[2 * H_ + h];
    accI[0] += qv[e] * wiq.x + kv[e] * wik.x + vv[e] * wiv.x;
    accI[1] += qv[e] * wiq.y + kv[e] * wik.y + vv[e] * wiv.y;
    accI[2] += qv[e] * wiq.z + kv[e] * wik.z + vv[e] * wiv.z;
    accI[3] += qv[e] * wiq.w + kv[e] * wik.w + vv[e] * wiv.w;
    accF[0] += qv[e] * wfq.x + kv[e] * wfk.x + vv[e] * wfv.x;
    accF[1] += qv[e] * wfq.y + kv[e] * wfk.y + vv[e] * wfv.y;
    accF[2] += qv[e] * wfq.z + kv[e] * wfk.z + vv[e] * wfv.z;
    accF[3] += qv[e] * wfq.w + kv[e] * wfk.w + vv[e] * wfv.w;
  }
#pragma unroll
  for (int n = 0; n < NH_; ++n) {
    for (int m = 1; m < 64; m <<= 1) {
      accI[n] += __shfl_xor(accI[n], m);
      accF[n] += __shfl_xor(accF[n], m);
    }
  }
  __shared__ float red[4][8];
  int wave = threadIdx.x >> 6;
  int lane = threadIdx.x & 63;
  if (lane == 0) {
#pragma unroll
    for (int n = 0; n < NH_; ++n) {
      red[wave][n] = accI[n];
      red[wave][4 + n] = accF[n];
    }
  }
  __syncthreads();
  if (threadIdx.x < 8) {
    int t = threadIdx.x;
    float sum = red[0][t] + red[1][t] + red[2][t] + red[3][t];
    if (t < 4) {
      int n = t;
      ig_pre[((size_t)(b * NH_ + n)) * S_ + s] = sum + igb[n];
    } else {
      int n = t - 4;
      float x = sum + fgb[n];
      float ls = (x >= 0.f) ? -log1pf(expf(-x)) : (x - log1pf(expf(x)));
      lsf[((size_t)(b * NH_ + n)) * S_ + s] = ls;
    }
  }
}

// ---------------------------------------------------------------------------
// Kernel 2: per-(b,nh) scan — in-register version (proven rounds 6-8).
// ---------------------------------------------------------------------------
__global__ __launch_bounds__(64) void scan_kernel(
    const float* __restrict__ ig_pre, const float* __restrict__ lsf,
    float* __restrict__ a_out, float* __restrict__ M_out,
    float* __restrict__ fl_out) {
  int hd = blockIdx.x;
  int lane = threadIdx.x;
  const float* ig = ig_pre + (size_t)hd * S_;
  const float* ls = lsf + (size_t)hd * S_;
  float xs[32], ys[32];
#pragma unroll
  for (int c = 0; c < 32; ++c) xs[c] = ls[c * 64 + lane];
#pragma unroll
  for (int c = 0; c < 32; ++c) ys[c] = ig[c * 64 + lane];

  float carry = 0.f;
  float mcarry = -INFINITY;
#pragma unroll
  for (int c = 0; c < 32; ++c) {
    int s = c * 64 + lane;
    float x = xs[c];
    for (int off = 1; off < 64; off <<= 1) {
      float t = __shfl_up(x, off);
      if (lane >= off) x += t;
    }
    float csum = carry + x;
    float a = ys[c] - csum;
    float y = a;
    for (int off = 1; off < 64; off <<= 1) {
      float t = __shfl_up(y, off);
      if (lane >= off) y = fmaxf(y, t);
    }
    float M = fmaxf(mcarry, y);
    a_out[(size_t)hd * S_ + s] = a;
    M_out[(size_t)hd * S_ + s] = M;
    fl_out[(size_t)hd * S_ + s] = expf(-(csum + M));
    carry = __shfl(csum, 63);
    mcarry = __shfl(M, 63);
  }
}

// ---------------------------------------------------------------------------
// Kernel 3: MFMA main kernel, 4-way j-split, 3 blocks/CU.
//   grid = 1024: bid = p*256 + idx; hd = idx&7, cs = idx>>3,
//   rtb = (p even) ? 31-cs : cs  (complement pairing for balance).
//   Block does j-tiles jt = p, p+4, ... <= 2*rtb+1  (<=16 iterations).
//   Partials atomicAdd'ed into po[]/rsb[] (memset-zeroed on stream).
// LDS: K [0,16384) row-major slot^(j&7); vT [16384,34816) stride-36 swizzled;
//      P [34816,39936) per-wave [16][40]. 39.9 KB -> 3 blocks/CU fits easily.
// launch_bounds(256,3): VGPR cap ~170 >= natural ~144 -> NO SPILL (round-8
// lesson: (256,4) forced 64 VGPR and 600 MB of scratch traffic).
// ---------------------------------------------------------------------------
#define VSTR 36
#define KOFF 0
#define VOFF 16384
#define POFF (16384 + 2 * VSTR * 256)
#define SMEM_BYTES (POFF + 4 * 1280)

__global__ __launch_bounds__(256, 3) void mlstm_mfma(
    const float* __restrict__ q, const float* __restrict__ k,
    const float* __restrict__ v,
    const float* __restrict__ a_arr, const float* __restrict__ M_arr,
    float* __restrict__ po, float* __restrict__ rsb) {
  __shared__ __align__(16) char smem[SMEM_BYTES];

  const int bid = blockIdx.x;
  const int p = bid >> 8;
  const int idx = bid & 255;
  const int hd = idx & 7;
  const int cs = idx >> 3;
  const int rtb = (p & 1) ? cs : 31 - cs;
  const int lim = 2 * rtb + 1;
  const int ntiles = (p <= lim) ? ((lim - p) >> 2) + 1 : 0;
  if (ntiles <= 0) return;

  const int b = hd >> 2, nh = hd & 3;
  const int i0 = rtb * 64;

  const int tid = threadIdx.x;
  const int wave = tid >> 6;
  const int l = tid & 63;
  const int g = l >> 4;      // 0..3
  const int c16 = l & 15;    // 0..15
  const int iw = i0 + wave * 16;

  const short8* kb8 = reinterpret_cast<const short8*>(smem + KOFF);
  short* vt = reinterpret_cast<short*>(smem + VOFF);
  short* pb = reinterpret_cast<short*>(smem + POFF + wave * 1280);

  // ---- Q A-fragments: row = iw + c16, k-elems = 32c + 8g + e ----
  short8 qf[8];
  {
    const float* qp = q + ((size_t)b * S_ + (iw + c16)) * H_ + nh * DH_;
#pragma unroll
    for (int c = 0; c < 8; ++c) {
      int d0 = c * 32 + g * 8;
      float4 f0 = *reinterpret_cast<const float4*>(qp + d0);
      float4 f1 = *reinterpret_cast<const float4*>(qp + d0 + 4);
      qf[c] = pack8(f0, f1);
    }
  }
  float Mr[4];
#pragma unroll
  for (int r = 0; r < 4; ++r)
    Mr[r] = M_arr[(size_t)hd * S_ + iw + 4 * g + r];

  f32x4 oa[16];
#pragma unroll
  for (int d = 0; d < 16; ++d) oa[d] = (f32x4){0.f, 0.f, 0.f, 0.f};
  float rs[4] = {0.f, 0.f, 0.f, 0.f};

  // staging maps
  const int sjk = tid >> 3;   // K row 0..31
  const int sck = tid & 7;    // K d-block of 32
  const int sjp = tid >> 4;   // V row-pair 0..15
  const int scv = tid & 15;   // V d-stripe base

  const float* kgb = k + (size_t)b * S_ * H_ + nh * DH_;
  const float* vgb = v + (size_t)b * S_ * H_ + nh * DH_;
  const float* agb = a_arr + (size_t)hd * S_;

  const int jtmaxW = (iw + 15) >> 5;  // causal cap per wave

  for (int n = 0; n < ntiles; ++n) {
    const int jt = p + 4 * n;
    const bool active = (jt <= jtmaxW);

    // ---- stage K ----
    {
      const float* kp = kgb + (size_t)(jt * 32 + sjk) * H_ + sck * 32;
      short8* krow8 = const_cast<short8*>(kb8) + sjk * 32;
#pragma unroll
      for (int u = 0; u < 4; ++u) {
        float4 a0 = *reinterpret_cast<const float4*>(kp + 8 * u);
        float4 a1 = *reinterpret_cast<const float4*>(kp + 8 * u + 4);
        int phys = (4 * sck + u) ^ (sjk & 7);
        krow8[phys] = pack8(a0, a1);
      }
    }
    // ---- stage V transposed ----
    {
      const float* vp0 = vgb + (size_t)(jt * 32 + 2 * sjp) * H_;
      const float* vp1 = vp0 + H_;
#pragma unroll
      for (int m = 0; m < 16; ++m) {
        int d = scv + 16 * m;
        int jph = (2 * sjp) ^ ((m & 3) << 3);
        short2v t;
        t[0] = f2bf(vp0[scv + 16 * m]);
        t[1] = f2bf(vp1[scv + 16 * m]);
        *reinterpret_cast<short2v*>(vt + d * VSTR + jph) = t;
      }
    }
    __syncthreads();  // staging visible to all waves

    if (active) {
      const int j0 = jt * 32;
      // ---- S = Q K^T ----
      f32x4 sa0 = {0.f, 0.f, 0.f, 0.f}, sa1 = {0.f, 0.f, 0.f, 0.f};
#pragma unroll
      for (int c = 0; c < 8; ++c) {
        int row0 = c16, row1 = 16 + c16;
        int slot = 4 * c + g;
        short8 kf0 = kb8[row0 * 32 + (slot ^ (row0 & 7))];
        short8 kf1 = kb8[row1 * 32 + (slot ^ (row1 & 7))];
        sa0 = __builtin_amdgcn_mfma_f32_16x16x32_bf16(qf[c], kf0, sa0, 0, 0, 0);
        sa1 = __builtin_amdgcn_mfma_f32_16x16x32_bf16(qf[c], kf1, sa1, 0, 0, 0);
      }
      // ---- weights, causal mask, rowsum, P -> wave-private LDS ----
      float a0 = agb[j0 + c16];
      float a1 = agb[j0 + 16 + c16];
#pragma unroll
      for (int r = 0; r < 4; ++r) {
        int i = iw + 4 * g + r;
        float w0 = sa0[r] * 0.0625f * __expf(a0 - Mr[r]);
        if (j0 + c16 > i) w0 = 0.f;
        float w1 = sa1[r] * 0.0625f * __expf(a1 - Mr[r]);
        if (j0 + 16 + c16 > i) w1 = 0.f;
        rs[r] += w0 + w1;
        pb[(4 * g + r) * 40 + c16]      = f2bf(w0);
        pb[(4 * g + r) * 40 + 16 + c16] = f2bf(w1);
      }
      asm volatile("" ::: "memory");
      short8 pa = *reinterpret_cast<const short8*>(pb + c16 * 40 + 8 * g);
      // ---- O += P V ----
#pragma unroll
      for (int dq = 0; dq < 16; ++dq) {
        short8 vf = *reinterpret_cast<const short8*>(
            vt + (16 * dq + c16) * VSTR + 8 * (g ^ (dq & 3)));
        oa[dq] = __builtin_amdgcn_mfma_f32_16x16x32_bf16(pa, vf, oa[dq], 0, 0, 0);
      }
    }
    __syncthreads();  // all waves done reading before next staging overwrite
  }

  // ---- waves that never computed contribute nothing (po is pre-zeroed) ----
  if (jtmaxW < p) return;

  // ---- rowsum reduce across the 16-lane group, then atomic accumulate ----
#pragma unroll
  for (int r = 0; r < 4; ++r) {
    rs[r] += __shfl_xor(rs[r], 1);
    rs[r] += __shfl_xor(rs[r], 2);
    rs[r] += __shfl_xor(rs[r], 4);
    rs[r] += __shfl_xor(rs[r], 8);
  }
  if (c16 == 0) {
#pragma unroll
    for (int r = 0; r < 4; ++r)
      atomicAdd(&rsb[hd * S_ + iw + 4 * g + r], rs[r]);
  }
#pragma unroll
  for (int dq = 0; dq < 16; ++dq)
#pragma unroll
    for (int r = 0; r < 4; ++r)
      atomicAdd(&po[((size_t)(hd * S_ + iw + 4 * g + r)) * DH_ + dq * 16 + c16],
                oa[dq][r]);
}

// ---------------------------------------------------------------------------
// Kernel 4: combine partials -> normalizer + multihead layernorm -> out.
// ---------------------------------------------------------------------------
__global__ __launch_bounds__(256) void combine_kernel(
    const float* __restrict__ po, const float* __restrict__ rsb,
    const float* __restrict__ fl_arr, const float* __restrict__ scale,
    float* __restrict__ out) {
  int ridx = blockIdx.x * 4 + (threadIdx.x >> 6);
  int lane = threadIdx.x & 63;
  int hd = ridx >> 11, i = ridx & 2047;
  int b = hd >> 2, nh = hd & 3;

  float4 a4 = *reinterpret_cast<const float4*>(
      po + ((size_t)(hd * S_ + i)) * DH_ + lane * 4);

  float rsum = rsb[hd * S_ + i];
  float fl = fl_arr[(size_t)hd * S_ + i];
  float inv = 1.f / (fmaxf(fabsf(rsum), fl) + 1e-6f);

  float o0 = a4.x * inv;
  float o1 = a4.y * inv;
  float o2 = a4.z * inv;
  float o3 = a4.w * inv;

  float s1 = o0 + o1 + o2 + o3;
  float s2 = o0 * o0 + o1 * o1 + o2 * o2 + o3 * o3;
#pragma unroll
  for (int m = 1; m < 64; m <<= 1) {
    s1 += __shfl_xor(s1, m);
    s2 += __shfl_xor(s2, m);
  }
  float mean = s1 * (1.f / DH_);
  float var = s2 * (1.f / DH_) - mean * mean;
  float rstd = rsqrtf(var + 1e-6f);

  const float* scp = scale + nh * DH_ + lane * 4;
  float4 res;
  res.x = (o0 - mean) * rstd * scp[0];
  res.y = (o1 - mean) * rstd * scp[1];
  res.z = (o2 - mean) * rstd * scp[2];
  res.w = (o3 - mean) * rstd * scp[3];
  float* op = out + ((size_t)b * S_ + i) * H_ + nh * DH_ + lane * 4;
  *reinterpret_cast<float4*>(op) = res;
}

// ---------------------------------------------------------------------------
extern "C" void kernel_launch(void* const* d_in, const int* in_sizes, int n_in,
                              void* d_out, int out_size, void* d_ws,
                              size_t ws_size, hipStream_t stream) {
  const float* q   = (const float*)d_in[0];
  const float* k   = (const float*)d_in[1];
  const float* v   = (const float*)d_in[2];
  const float* igk = (const float*)d_in[3];
  const float* igb = (const float*)d_in[4];
  const float* fgk = (const float*)d_in[5];
  const float* fgb = (const float*)d_in[6];
  const float* scl = (const float*)d_in[7];
  float* out = (float*)d_out;

  const size_t seq = (size_t)B_ * NH_ * S_;  // 16384
  float* ws = (float*)d_ws;
  float* ig_pre = ws;
  float* lsf    = ws + seq;
  float* a_arr  = ws + 2 * seq;
  float* M_arr  = ws + 3 * seq;
  float* fl_arr = ws + 4 * seq;
  float* rsb    = ws + 5 * seq;
  float* po     = ws + 6 * seq;   // 8*2048*256 floats = 16.8 MB

  hipMemsetAsync(po, 0, (size_t)8 * 2048 * 256 * 4, stream);
  hipMemsetAsync(rsb, 0, seq * 4, stream);
  gates_kernel<<<B_ * S_, 256, 0, stream>>>(q, k, v, igk, igb, fgk, fgb,
                                            ig_pre, lsf);
  scan_kernel<<<B_ * NH_, 64, 0, stream>>>(ig_pre, lsf, a_arr, M_arr, fl_arr);
  mlstm_mfma<<<1024, 256, 0, stream>>>(q, k, v, a_arr, M_arr, po, rsb);
  combine_kernel<<<B_ * NH_ * S_ / 4, 256, 0, stream>>>(
      po, rsb, fl_arr, scl, out);
}

// Round 10
// 238.089 us; speedup vs baseline: 1.6930x; 1.3457x over previous
//
#include <hip/hip_runtime.h>
#include <hip/hip_bf16.h>
#include <math.h>

#define B_  2
#define S_  2048
#define H_  1024
#define NH_ 4
#define DH_ 256

typedef __attribute__((ext_vector_type(8))) short short8;
typedef __attribute__((ext_vector_type(2))) short short2v;
typedef __attribute__((ext_vector_type(4))) float f32x4;

static __device__ __forceinline__ short f2bf(float x) {
  __hip_bfloat16 h = __float2bfloat16(x);
  union { __hip_bfloat16 h; short s; } u;
  u.h = h;
  return u.s;
}

static __device__ __forceinline__ short8 pack8(const float4& a, const float4& b) {
  short8 t;
  t[0] = f2bf(a.x); t[1] = f2bf(a.y); t[2] = f2bf(a.z); t[3] = f2bf(a.w);
  t[4] = f2bf(b.x); t[5] = f2bf(b.y); t[6] = f2bf(b.z); t[7] = f2bf(b.w);
  return t;
}

// ---------------------------------------------------------------------------
// Kernel 1: gate projections (float4 h-vectorized, proven rounds 8/9).
// ---------------------------------------------------------------------------
__global__ __launch_bounds__(256) void gates_kernel(
    const float* __restrict__ q, const float* __restrict__ k,
    const float* __restrict__ v,
    const float* __restrict__ igk, const float* __restrict__ igb,
    const float* __restrict__ fgk, const float* __restrict__ fgb,
    float* __restrict__ ig_pre, float* __restrict__ lsf) {
  int bs = blockIdx.x;
  int b = bs / S_, s = bs % S_;
  const float* qrow = q + ((size_t)b * S_ + s) * H_;
  const float* krow = k + ((size_t)b * S_ + s) * H_;
  const float* vrow = v + ((size_t)b * S_ + s) * H_;

  int h0 = threadIdx.x * 4;
  float4 q4 = *reinterpret_cast<const float4*>(qrow + h0);
  float4 k4 = *reinterpret_cast<const float4*>(krow + h0);
  float4 v4 = *reinterpret_cast<const float4*>(vrow + h0);
  float qv[4] = {q4.x, q4.y, q4.z, q4.w};
  float kv[4] = {k4.x, k4.y, k4.z, k4.w};
  float vv[4] = {v4.x, v4.y, v4.z, v4.w};

  const float4* igk4 = reinterpret_cast<const float4*>(igk);
  const float4* fgk4 = reinterpret_cast<const float4*>(fgk);

  float accI[NH_] = {0.f, 0.f, 0.f, 0.f};
  float accF[NH_] = {0.f, 0.f, 0.f, 0.f};
#pragma unroll
  for (int e = 0; e < 4; ++e) {
    int h = h0 + e;
    float4 wiq = igk4[h], wik = igk4[H_ + h], wiv = igk4[2 * H_ + h];
    float4 wfq = fgk4[h], wfk = fgk4[H_ + h], wfv = fgk4[2 * H_ + h];
    accI[0] += qv[e] * wiq.x + kv[e] * wik.x + vv[e] * wiv.x;
    accI[1] += qv[e] * wiq.y + kv[e] * wik.y + vv[e] * wiv.y;
    accI[2] += qv[e] * wiq.z + kv[e] * wik.z + vv[e] * wiv.z;
    accI[3] += qv[e] * wiq.w + kv[e] * wik.w + vv[e] * wiv.w;
    accF[0] += qv[e] * wfq.x + kv[e] * wfk.x + vv[e] * wfv.x;
    accF[1] += qv[e] * wfq.y + kv[e] * wfk.y + vv[e] * wfv.y;
    accF[2] += qv[e] * wfq.z + kv[e] * wfk.z + vv[e] * wfv.z;
    accF[3] += qv[e] * wfq.w + kv[e] * wfk.w + vv[e] * wfv.w;
  }
#pragma unroll
  for (int n = 0; n < NH_; ++n) {
    for (int m = 1; m < 64; m <<= 1) {
      accI[n] += __shfl_xor(accI[n], m);
      accF[n] += __shfl_xor(accF[n], m);
    }
  }
  __shared__ float red[4][8];
  int wave = threadIdx.x >> 6;
  int lane = threadIdx.x & 63;
  if (lane == 0) {
#pragma unroll
    for (int n = 0; n < NH_; ++n) {
      red[wave][n] = accI[n];
      red[wave][4 + n] = accF[n];
    }
  }
  __syncthreads();
  if (threadIdx.x < 8) {
    int t = threadIdx.x;
    float sum = red[0][t] + red[1][t] + red[2][t] + red[3][t];
    if (t < 4) {
      int n = t;
      ig_pre[((size_t)(b * NH_ + n)) * S_ + s] = sum + igb[n];
    } else {
      int n = t - 4;
      float x = sum + fgb[n];
      float ls = (x >= 0.f) ? -log1pf(expf(-x)) : (x - log1pf(expf(x)));
      lsf[((size_t)(b * NH_ + n)) * S_ + s] = ls;
    }
  }
}

// ---------------------------------------------------------------------------
// Kernel 2: per-(b,nh) scan — in-register version (proven rounds 6-9).
// ---------------------------------------------------------------------------
__global__ __launch_bounds__(64) void scan_kernel(
    const float* __restrict__ ig_pre, const float* __restrict__ lsf,
    float* __restrict__ a_out, float* __restrict__ M_out,
    float* __restrict__ fl_out) {
  int hd = blockIdx.x;
  int lane = threadIdx.x;
  const float* ig = ig_pre + (size_t)hd * S_;
  const float* ls = lsf + (size_t)hd * S_;
  float xs[32], ys[32];
#pragma unroll
  for (int c = 0; c < 32; ++c) xs[c] = ls[c * 64 + lane];
#pragma unroll
  for (int c = 0; c < 32; ++c) ys[c] = ig[c * 64 + lane];

  float carry = 0.f;
  float mcarry = -INFINITY;
#pragma unroll
  for (int c = 0; c < 32; ++c) {
    int s = c * 64 + lane;
    float x = xs[c];
    for (int off = 1; off < 64; off <<= 1) {
      float t = __shfl_up(x, off);
      if (lane >= off) x += t;
    }
    float csum = carry + x;
    float a = ys[c] - csum;
    float y = a;
    for (int off = 1; off < 64; off <<= 1) {
      float t = __shfl_up(y, off);
      if (lane >= off) y = fmaxf(y, t);
    }
    float M = fmaxf(mcarry, y);
    a_out[(size_t)hd * S_ + s] = a;
    M_out[(size_t)hd * S_ + s] = M;
    fl_out[(size_t)hd * S_ + s] = expf(-(csum + M));
    carry = __shfl(csum, 63);
    mcarry = __shfl(M, 63);
  }
}

// ---------------------------------------------------------------------------
// Kernel 3: MFMA main kernel, 4-way j-split, 2 blocks/CU, T14 prefetch.
//   grid = 1024: bid = p*256 + idx; hd = idx&7 (XCD-affine), cs = idx>>3,
//   rtb = (p even) ? 31-cs : cs  -> each CU's 4 blocks sum to ~33 tiles and
//   resolve to two ~16-tile streams running concurrently (2 blocks/CU).
//   Partials atomicAdd'ed into po[]/rsb[] (memset-zeroed on stream).
// LDS: K  [0,16384)          row-major, slot^(j&7)
//      V0 [16384,34816)      vT stride-36 swizzled (d-stripe writes)
//      V1 [34816,53248)      second V buffer (prefetch target)
//      P  [53248,58368)      per-wave [16][40]
// Pipeline/tile: stage_load(jt+4) -> QK -> bar1 -> exp/P/PV -> write_k +
//   write_v(other) -> bar2.   (K single-buffered: safe after bar1.)
// launch_bounds(256,2): unified reg cap 256 >= natural 144 VGPR + 64 AGPR
//   = 208 -> NO SPILL (rounds 8/9 lesson: caps 128/170 both forced spill).
// ---------------------------------------------------------------------------
#define VSTR 36
#define KOFF 0
#define VOFF0 16384
#define VOFF1 34816
#define POFF 53248
#define SMEM_BYTES (POFF + 4 * 1280)

__global__ __launch_bounds__(256, 2) void mlstm_mfma(
    const float* __restrict__ q, const float* __restrict__ k,
    const float* __restrict__ v,
    const float* __restrict__ a_arr, const float* __restrict__ M_arr,
    float* __restrict__ po, float* __restrict__ rsb) {
  __shared__ __align__(16) char smem[SMEM_BYTES];

  const int bid = blockIdx.x;
  const int p = bid >> 8;
  const int idx = bid & 255;
  const int hd = idx & 7;
  const int cs = idx >> 3;
  const int rtb = (p & 1) ? cs : 31 - cs;
  const int lim = 2 * rtb + 1;
  const int ntiles = (p <= lim) ? ((lim - p) >> 2) + 1 : 0;
  if (ntiles <= 0) return;

  const int b = hd >> 2, nh = hd & 3;
  const int i0 = rtb * 64;

  const int tid = threadIdx.x;
  const int wave = tid >> 6;
  const int l = tid & 63;
  const int g = l >> 4;      // 0..3
  const int c16 = l & 15;    // 0..15
  const int iw = i0 + wave * 16;

  const short8* kb8 = reinterpret_cast<const short8*>(smem + KOFF);
  short* pb = reinterpret_cast<short*>(smem + POFF + wave * 1280);

  // ---- Q A-fragments: row = iw + c16, k-elems = 32c + 8g + e ----
  short8 qf[8];
  {
    const float* qp = q + ((size_t)b * S_ + (iw + c16)) * H_ + nh * DH_;
#pragma unroll
    for (int c = 0; c < 8; ++c) {
      int d0 = c * 32 + g * 8;
      float4 f0 = *reinterpret_cast<const float4*>(qp + d0);
      float4 f1 = *reinterpret_cast<const float4*>(qp + d0 + 4);
      qf[c] = pack8(f0, f1);
    }
  }
  float Mr[4];
#pragma unroll
  for (int r = 0; r < 4; ++r)
    Mr[r] = M_arr[(size_t)hd * S_ + iw + 4 * g + r];

  f32x4 oa[16];
#pragma unroll
  for (int d = 0; d < 16; ++d) oa[d] = (f32x4){0.f, 0.f, 0.f, 0.f};
  float rs[4] = {0.f, 0.f, 0.f, 0.f};

  // staging maps
  const int sjk = tid >> 3;   // K row 0..31
  const int sck = tid & 7;    // K d-block of 32
  const int sjp = tid >> 4;   // V row-pair 0..15
  const int scv = tid & 15;   // V d-stripe base

  const float* kgb = k + (size_t)b * S_ * H_ + nh * DH_;
  const float* vgb = v + (size_t)b * S_ * H_ + nh * DH_;
  const float* agb = a_arr + (size_t)hd * S_;

  const int jtmaxW = (iw + 15) >> 5;  // causal cap per wave

  float4 kr[8];
  float va[16], vb[16];

  auto stage_load = [&](int jt) {
    const float* kp = kgb + (size_t)(jt * 32 + sjk) * H_ + sck * 32;
#pragma unroll
    for (int u = 0; u < 8; ++u)
      kr[u] = *reinterpret_cast<const float4*>(kp + 4 * u);
    const float* vp0 = vgb + (size_t)(jt * 32 + 2 * sjp) * H_;
    const float* vp1 = vp0 + H_;
#pragma unroll
    for (int m = 0; m < 16; ++m) {
      va[m] = vp0[scv + 16 * m];
      vb[m] = vp1[scv + 16 * m];
    }
  };

  auto write_k = [&]() {
    short8* krow8 = const_cast<short8*>(kb8) + sjk * 32;
#pragma unroll
    for (int u = 0; u < 4; ++u) {
      int phys = (4 * sck + u) ^ (sjk & 7);
      krow8[phys] = pack8(kr[2 * u], kr[2 * u + 1]);
    }
  };

  auto write_v = [&](int buf) {
    short* vt = reinterpret_cast<short*>(smem + (buf ? VOFF1 : VOFF0));
#pragma unroll
    for (int m = 0; m < 16; ++m) {
      int d = scv + 16 * m;                 // d-stripe: conflict-free writes
      int jph = (2 * sjp) ^ ((m & 3) << 3);
      short2v t;
      t[0] = f2bf(va[m]);
      t[1] = f2bf(vb[m]);
      *reinterpret_cast<short2v*>(vt + d * VSTR + jph) = t;
    }
  };

  // prologue: first tile of this parity
  stage_load(p);
  write_k();
  write_v(0);
  __syncthreads();

  for (int n = 0; n < ntiles; ++n) {
    const int jt = p + 4 * n;
    const int cur = n & 1;
    const bool last = (n == ntiles - 1);
    const bool active = (jt <= jtmaxW);

    if (!last) stage_load(jt + 4);  // globals in flight during compute

    // ---- S = Q K^T (two 16-wide j sub-tiles) ----
    f32x4 sa0 = {0.f, 0.f, 0.f, 0.f}, sa1 = {0.f, 0.f, 0.f, 0.f};
    if (active) {
#pragma unroll
      for (int c = 0; c < 8; ++c) {
        int row0 = c16, row1 = 16 + c16;
        int slot = 4 * c + g;
        short8 kf0 = kb8[row0 * 32 + (slot ^ (row0 & 7))];
        short8 kf1 = kb8[row1 * 32 + (slot ^ (row1 & 7))];
        sa0 = __builtin_amdgcn_mfma_f32_16x16x32_bf16(qf[c], kf0, sa0, 0, 0, 0);
        sa1 = __builtin_amdgcn_mfma_f32_16x16x32_bf16(qf[c], kf1, sa1, 0, 0, 0);
      }
    }
    __syncthreads();  // bar1: all waves done reading K

    if (active) {
      const int j0 = jt * 32;
      float a0 = agb[j0 + c16];
      float a1 = agb[j0 + 16 + c16];
#pragma unroll
      for (int r = 0; r < 4; ++r) {
        int i = iw + 4 * g + r;
        float w0 = sa0[r] * 0.0625f * __expf(a0 - Mr[r]);
        if (j0 + c16 > i) w0 = 0.f;
        float w1 = sa1[r] * 0.0625f * __expf(a1 - Mr[r]);
        if (j0 + 16 + c16 > i) w1 = 0.f;
        rs[r] += w0 + w1;
        pb[(4 * g + r) * 40 + c16]      = f2bf(w0);
        pb[(4 * g + r) * 40 + 16 + c16] = f2bf(w1);
      }
      asm volatile("" ::: "memory");
      short8 pa = *reinterpret_cast<const short8*>(pb + c16 * 40 + 8 * g);
      const short* vt = reinterpret_cast<const short*>(smem + (cur ? VOFF1 : VOFF0));
#pragma unroll
      for (int dq = 0; dq < 16; ++dq) {
        short8 vf = *reinterpret_cast<const short8*>(
            vt + (16 * dq + c16) * VSTR + 8 * (g ^ (dq & 3)));
        oa[dq] = __builtin_amdgcn_mfma_f32_16x16x32_bf16(pa, vf, oa[dq], 0, 0, 0);
      }
    }

    if (!last) {
      write_k();            // safe: all QK reads of this tile passed bar1
      write_v(cur ^ 1);     // other buffer; current PV reads V[cur]
    }
    __syncthreads();  // bar2: next tile staged / all PV reads done
  }

  // ---- waves that never computed contribute nothing (po is pre-zeroed) ----
  if (jtmaxW < p) return;

  // ---- rowsum reduce across the 16-lane group, then atomic accumulate ----
#pragma unroll
  for (int r = 0; r < 4; ++r) {
    rs[r] += __shfl_xor(rs[r], 1);
    rs[r] += __shfl_xor(rs[r], 2);
    rs[r] += __shfl_xor(rs[r], 4);
    rs[r] += __shfl_xor(rs[r], 8);
  }
  if (c16 == 0) {
#pragma unroll
    for (int r = 0; r < 4; ++r)
      atomicAdd(&rsb[hd * S_ + iw + 4 * g + r], rs[r]);
  }
#pragma unroll
  for (int dq = 0; dq < 16; ++dq)
#pragma unroll
    for (int r = 0; r < 4; ++r)
      atomicAdd(&po[((size_t)(hd * S_ + iw + 4 * g + r)) * DH_ + dq * 16 + c16],
                oa[dq][r]);
}

// ---------------------------------------------------------------------------
// Kernel 4: combine partials -> normalizer + multihead layernorm -> out.
// ---------------------------------------------------------------------------
__global__ __launch_bounds__(256) void combine_kernel(
    const float* __restrict__ po, const float* __restrict__ rsb,
    const float* __restrict__ fl_arr, const float* __restrict__ scale,
    float* __restrict__ out) {
  int ridx = blockIdx.x * 4 + (threadIdx.x >> 6);
  int lane = threadIdx.x & 63;
  int hd = ridx >> 11, i = ridx & 2047;
  int b = hd >> 2, nh = hd & 3;

  float4 a4 = *reinterpret_cast<const float4*>(
      po + ((size_t)(hd * S_ + i)) * DH_ + lane * 4);

  float rsum = rsb[hd * S_ + i];
  float fl = fl_arr[(size_t)hd * S_ + i];
  float inv = 1.f / (fmaxf(fabsf(rsum), fl) + 1e-6f);

  float o0 = a4.x * inv;
  float o1 = a4.y * inv;
  float o2 = a4.z * inv;
  float o3 = a4.w * inv;

  float s1 = o0 + o1 + o2 + o3;
  float s2 = o0 * o0 + o1 * o1 + o2 * o2 + o3 * o3;
#pragma unroll
  for (int m = 1; m < 64; m <<= 1) {
    s1 += __shfl_xor(s1, m);
    s2 += __shfl_xor(s2, m);
  }
  float mean = s1 * (1.f / DH_);
  float var = s2 * (1.f / DH_) - mean * mean;
  float rstd = rsqrtf(var + 1e-6f);

  const float* scp = scale + nh * DH_ + lane * 4;
  float4 res;
  res.x = (o0 - mean) * rstd * scp[0];
  res.y = (o1 - mean) * rstd * scp[1];
  res.z = (o2 - mean) * rstd * scp[2];
  res.w = (o3 - mean) * rstd * scp[3];
  float* op = out + ((size_t)b * S_ + i) * H_ + nh * DH_ + lane * 4;
  *reinterpret_cast<float4*>(op) = res;
}

// ---------------------------------------------------------------------------
extern "C" void kernel_launch(void* const* d_in, const int* in_sizes, int n_in,
                              void* d_out, int out_size, void* d_ws,
                              size_t ws_size, hipStream_t stream) {
  const float* q   = (const float*)d_in[0];
  const float* k   = (const float*)d_in[1];
  const float* v   = (const float*)d_in[2];
  const float* igk = (const float*)d_in[3];
  const float* igb = (const float*)d_in[4];
  const float* fgk = (const float*)d_in[5];
  const float* fgb = (const float*)d_in[6];
  const float* scl = (const float*)d_in[7];
  float* out = (float*)d_out;

  const size_t seq = (size_t)B_ * NH_ * S_;  // 16384
  float* ws = (float*)d_ws;
  float* ig_pre = ws;
  float* lsf    = ws + seq;
  float* a_arr  = ws + 2 * seq;
  float* M_arr  = ws + 3 * seq;
  float* fl_arr = ws + 4 * seq;
  float* rsb    = ws + 5 * seq;
  float* po     = ws + 6 * seq;   // 8*2048*256 floats = 16.8 MB

  hipMemsetAsync(po, 0, (size_t)8 * 2048 * 256 * 4, stream);
  hipMemsetAsync(rsb, 0, seq * 4, stream);
  gates_kernel<<<B_ * S_, 256, 0, stream>>>(q, k, v, igk, igb, fgk, fgb,
                                            ig_pre, lsf);
  scan_kernel<<<B_ * NH_, 64, 0, stream>>>(ig_pre, lsf, a_arr, M_arr, fl_arr);
  mlstm_mfma<<<1024, 256, 0, stream>>>(q, k, v, a_arr, M_arr, po, rsb);
  combine_kernel<<<B_ * NH_ * S_ / 4, 256, 0, stream>>>(
      po, rsb, fl_arr, scl, out);
}

// Round 11
// 211.685 us; speedup vs baseline: 1.9041x; 1.1247x over previous
//
#include <hip/hip_runtime.h>
#include <hip/hip_bf16.h>
#include <math.h>

#define B_  2
#define S_  2048
#define H_  1024
#define NH_ 4
#define DH_ 256

typedef __attribute__((ext_vector_type(8))) short short8;
typedef __attribute__((ext_vector_type(4))) short short4v;
typedef __attribute__((ext_vector_type(2))) short short2v;
typedef __attribute__((ext_vector_type(4))) float f32x4;

#define KTILE_BYTES 16384   // 32 rows x 256 d x 2B (swizzled slots)
#define VTILE_BYTES 18432   // 256 d x 36 shorts (transposed, swizzled, padded)

static __device__ __forceinline__ short f2bf(float x) {
  __hip_bfloat16 h = __float2bfloat16(x);
  union { __hip_bfloat16 h; short s; } u;
  u.h = h;
  return u.s;
}

static __device__ __forceinline__ short8 pack8(const float4& a, const float4& b) {
  short8 t;
  t[0] = f2bf(a.x); t[1] = f2bf(a.y); t[2] = f2bf(a.z); t[3] = f2bf(a.w);
  t[4] = f2bf(b.x); t[5] = f2bf(b.y); t[6] = f2bf(b.z); t[7] = f2bf(b.w);
  return t;
}

// global -> LDS DMA. LDS dest is wave-uniform; HW adds lane*size.
static __device__ __forceinline__ void gload16(const void* g, void* l) {
  __builtin_amdgcn_global_load_lds(
      (const __attribute__((address_space(1))) unsigned int*)g,
      (__attribute__((address_space(3))) unsigned int*)l, 16, 0, 0);
}
static __device__ __forceinline__ void gload4(const void* g, void* l) {
  __builtin_amdgcn_global_load_lds(
      (const __attribute__((address_space(1))) unsigned int*)g,
      (__attribute__((address_space(3))) unsigned int*)l, 4, 0, 0);
}

// ---------------------------------------------------------------------------
// Kernel 1: gate projections (float4 h-vectorized, proven rounds 8-10).
// ---------------------------------------------------------------------------
__global__ __launch_bounds__(256) void gates_kernel(
    const float* __restrict__ q, const float* __restrict__ k,
    const float* __restrict__ v,
    const float* __restrict__ igk, const float* __restrict__ igb,
    const float* __restrict__ fgk, const float* __restrict__ fgb,
    float* __restrict__ ig_pre, float* __restrict__ lsf) {
  int bs = blockIdx.x;
  int b = bs / S_, s = bs % S_;
  const float* qrow = q + ((size_t)b * S_ + s) * H_;
  const float* krow = k + ((size_t)b * S_ + s) * H_;
  const float* vrow = v + ((size_t)b * S_ + s) * H_;

  int h0 = threadIdx.x * 4;
  float4 q4 = *reinterpret_cast<const float4*>(qrow + h0);
  float4 k4 = *reinterpret_cast<const float4*>(krow + h0);
  float4 v4 = *reinterpret_cast<const float4*>(vrow + h0);
  float qv[4] = {q4.x, q4.y, q4.z, q4.w};
  float kv[4] = {k4.x, k4.y, k4.z, k4.w};
  float vv[4] = {v4.x, v4.y, v4.z, v4.w};

  const float4* igk4 = reinterpret_cast<const float4*>(igk);
  const float4* fgk4 = reinterpret_cast<const float4*>(fgk);

  float accI[NH_] = {0.f, 0.f, 0.f, 0.f};
  float accF[NH_] = {0.f, 0.f, 0.f, 0.f};
#pragma unroll
  for (int e = 0; e < 4; ++e) {
    int h = h0 + e;
    float4 wiq = igk4[h], wik = igk4[H_ + h], wiv = igk4[2 * H_ + h];
    float4 wfq = fgk4[h], wfk = fgk4[H_ + h], wfv = fgk4[2 * H_ + h];
    accI[0] += qv[e] * wiq.x + kv[e] * wik.x + vv[e] * wiv.x;
    accI[1] += qv[e] * wiq.y + kv[e] * wik.y + vv[e] * wiv.y;
    accI[2] += qv[e] * wiq.z + kv[e] * wik.z + vv[e] * wiv.z;
    accI[3] += qv[e] * wiq.w + kv[e] * wik.w + vv[e] * wiv.w;
    accF[0] += qv[e] * wfq.x + kv[e] * wfk.x + vv[e] * wfv.x;
    accF[1] += qv[e] * wfq.y + kv[e] * wfk.y + vv[e] * wfv.y;
    accF[2] += qv[e] * wfq.z + kv[e] * wfk.z + vv[e] * wfv.z;
    accF[3] += qv[e] * wfq.w + kv[e] * wfk.w + vv[e] * wfv.w;
  }
#pragma unroll
  for (int n = 0; n < NH_; ++n) {
    for (int m = 1; m < 64; m <<= 1) {
      accI[n] += __shfl_xor(accI[n], m);
      accF[n] += __shfl_xor(accF[n], m);
    }
  }
  __shared__ float red[4][8];
  int wave = threadIdx.x >> 6;
  int lane = threadIdx.x & 63;
  if (lane == 0) {
#pragma unroll
    for (int n = 0; n < NH_; ++n) {
      red[wave][n] = accI[n];
      red[wave][4 + n] = accF[n];
    }
  }
  __syncthreads();
  if (threadIdx.x < 8) {
    int t = threadIdx.x;
    float sum = red[0][t] + red[1][t] + red[2][t] + red[3][t];
    if (t < 4) {
      int n = t;
      ig_pre[((size_t)(b * NH_ + n)) * S_ + s] = sum + igb[n];
    } else {
      int n = t - 4;
      float x = sum + fgb[n];
      float ls = (x >= 0.f) ? -log1pf(expf(-x)) : (x - log1pf(expf(x)));
      lsf[((size_t)(b * NH_ + n)) * S_ + s] = ls;
    }
  }
}

// ---------------------------------------------------------------------------
// Kernel 2: per-(b,nh) scan — in-register (proven rounds 6-10).
// ---------------------------------------------------------------------------
__global__ __launch_bounds__(64) void scan_kernel(
    const float* __restrict__ ig_pre, const float* __restrict__ lsf,
    float* __restrict__ a_out, float* __restrict__ M_out,
    float* __restrict__ fl_out) {
  int hd = blockIdx.x;
  int lane = threadIdx.x;
  const float* ig = ig_pre + (size_t)hd * S_;
  const float* ls = lsf + (size_t)hd * S_;
  float xs[32], ys[32];
#pragma unroll
  for (int c = 0; c < 32; ++c) xs[c] = ls[c * 64 + lane];
#pragma unroll
  for (int c = 0; c < 32; ++c) ys[c] = ig[c * 64 + lane];

  float carry = 0.f;
  float mcarry = -INFINITY;
#pragma unroll
  for (int c = 0; c < 32; ++c) {
    int s = c * 64 + lane;
    float x = xs[c];
    for (int off = 1; off < 64; off <<= 1) {
      float t = __shfl_up(x, off);
      if (lane >= off) x += t;
    }
    float csum = carry + x;
    float a = ys[c] - csum;
    float y = a;
    for (int off = 1; off < 64; off <<= 1) {
      float t = __shfl_up(y, off);
      if (lane >= off) y = fmaxf(y, t);
    }
    float M = fmaxf(mcarry, y);
    a_out[(size_t)hd * S_ + s] = a;
    M_out[(size_t)hd * S_ + s] = M;
    fl_out[(size_t)hd * S_ + s] = expf(-(csum + M));
    carry = __shfl(csum, 63);
    mcarry = __shfl(M, 63);
  }
}

// ---------------------------------------------------------------------------
// Kernel 2b: pack K and V tiles to bf16 global images that are byte-exact
// LDS layouts (swizzles baked in), so the main kernel can stage via
// global_load_lds with zero VGPR traffic and zero conversions.
//   K image (per 32-row tile): byte (j*512 + ((slot)^(j&7))*16), slot=d/8.
//   V image: short index d*36 + (j ^ (((d>>4)&3)<<3)); 4 pad shorts per d.
// grid = 8 heads * 64 tiles; 256 threads.
// ---------------------------------------------------------------------------
__global__ __launch_bounds__(256) void pack_kv(
    const float* __restrict__ k, const float* __restrict__ v,
    char* __restrict__ kpack, char* __restrict__ vpack) {
  const int bidx = blockIdx.x;
  const int hd = bidx & 7, jt = bidx >> 3;
  const int b = hd >> 2, nh = hd & 3;
  const float* kgb = k + ((size_t)b * S_ + jt * 32) * H_ + nh * DH_;
  const float* vgb = v + ((size_t)b * S_ + jt * 32) * H_ + nh * DH_;
  char* kp = kpack + ((size_t)(hd * 64 + jt)) * KTILE_BYTES;
  char* vp = vpack + ((size_t)(hd * 64 + jt)) * VTILE_BYTES;
  const int tid = threadIdx.x;

  // ---- K: thread = (row j, d-block of 32) ----
  {
    int j = tid >> 3, sck = tid & 7;
    const float* row = kgb + (size_t)j * H_ + sck * 32;
    short8* out8 = reinterpret_cast<short8*>(kp) + j * 32;
#pragma unroll
    for (int u = 0; u < 4; ++u) {
      float4 a0 = *reinterpret_cast<const float4*>(row + 8 * u);
      float4 a1 = *reinterpret_cast<const float4*>(row + 8 * u + 4);
      out8[(4 * sck + u) ^ (j & 7)] = pack8(a0, a1);
    }
  }
  // ---- V: thread = one d column; swizzled read order, linear 72B write ----
  {
    int d = tid;
    int jsw = ((d >> 4) & 3) << 3;
    short4v* dst = reinterpret_cast<short4v*>(vp + (size_t)d * 72);
#pragma unroll
    for (int c = 0; c < 8; ++c) {
      short4v t;
#pragma unroll
      for (int e = 0; e < 4; ++e)
        t[e] = f2bf(vgb[(size_t)((4 * c + e) ^ jsw) * H_ + d]);
      dst[c] = t;
    }
    short4v z = {0, 0, 0, 0};
    dst[8] = z;
  }
}

// ---------------------------------------------------------------------------
// Kernel 3: MFMA main. 4-way parity split (proven R10 grid), DMA staging.
//   grid 1024: p=bid>>8, idx=bid&255, hd=idx&7 (XCD-affine), cs=idx>>3,
//   rtb=(p&1)?cs:31-cs. Block does tiles jt=p,p+4,... (<=8 iters).
// LDS (double-buffered K and V, DMA-written):
//   K0 [0,16384) K1 [16384,32768) V0 [32768,51200) V1 [51200,69632)
//   P  [69632,74752) per-wave [16][40] shorts.
// Loop: issue 10 global_load_lds (next tile) -> compute(cur) -> one
// __syncthreads (its vmcnt(0) drain IS the pipeline wait). 1 barrier/iter.
// Partial O atomicAdd'ed directly into d_out (zeroed); combine is in-place.
// ---------------------------------------------------------------------------
#define KOFF0 0
#define KOFF1 16384
#define VOFF0 32768
#define VOFF1 51200
#define POFF  69632
#define SMEM_BYTES (POFF + 4 * 1280)
#define VSTR 36

__global__ __launch_bounds__(256, 2) void mlstm_mfma(
    const float* __restrict__ q,
    const float* __restrict__ a_arr, const float* __restrict__ M_arr,
    const char* __restrict__ kpack, const char* __restrict__ vpack,
    float* __restrict__ outacc, float* __restrict__ rsb) {
  __shared__ __align__(16) char smem[SMEM_BYTES];

  const int bid = blockIdx.x;
  const int p = bid >> 8;
  const int idx = bid & 255;
  const int hd = idx & 7;
  const int cs = idx >> 3;
  const int rtb = (p & 1) ? cs : 31 - cs;
  const int lim = 2 * rtb + 1;
  const int ntiles = (p <= lim) ? ((lim - p) >> 2) + 1 : 0;
  if (ntiles <= 0) return;

  const int b = hd >> 2, nh = hd & 3;
  const int i0 = rtb * 64;

  const int tid = threadIdx.x;
  const int wave = tid >> 6;
  const int l = tid & 63;
  const int g = l >> 4;      // 0..3
  const int c16 = l & 15;    // 0..15
  const int iw = i0 + wave * 16;

  short* pb = reinterpret_cast<short*>(smem + POFF + wave * 1280);
  const char* ktiles = kpack + (size_t)hd * 64 * KTILE_BYTES;
  const char* vtiles = vpack + (size_t)hd * 64 * VTILE_BYTES;

  // ---- Q A-fragments: row = iw + c16, k-elems = 32c + 8g + e ----
  short8 qf[8];
  {
    const float* qp = q + ((size_t)b * S_ + (iw + c16)) * H_ + nh * DH_;
#pragma unroll
    for (int c = 0; c < 8; ++c) {
      int d0 = c * 32 + g * 8;
      float4 f0 = *reinterpret_cast<const float4*>(qp + d0);
      float4 f1 = *reinterpret_cast<const float4*>(qp + d0 + 4);
      qf[c] = pack8(f0, f1);
    }
  }
  float Mr[4];
#pragma unroll
  for (int r = 0; r < 4; ++r)
    Mr[r] = M_arr[(size_t)hd * S_ + iw + 4 * g + r];

  f32x4 oa[16];
#pragma unroll
  for (int d = 0; d < 16; ++d) oa[d] = (f32x4){0.f, 0.f, 0.f, 0.f};
  float rs[4] = {0.f, 0.f, 0.f, 0.f};

  const float* agb = a_arr + (size_t)hd * S_;
  const int jtmaxW = (iw + 15) >> 5;  // causal cap per wave

  // DMA stage: 4x16B K + 4x16B V + 2x4B V tail per wave (wave-uniform dest)
  auto stage = [&](int jt, int buf) {
    const char* kt = ktiles + (size_t)jt * KTILE_BYTES + wave * 4096;
    char* kl = smem + (buf ? KOFF1 : KOFF0) + wave * 4096;
#pragma unroll
    for (int u = 0; u < 4; ++u)
      gload16(kt + u * 1024 + l * 16, kl + u * 1024);
    const char* vt = vtiles + (size_t)jt * VTILE_BYTES + wave * 4608;
    char* vl = smem + (buf ? VOFF1 : VOFF0) + wave * 4608;
#pragma unroll
    for (int u = 0; u < 4; ++u)
      gload16(vt + u * 1024 + l * 16, vl + u * 1024);
#pragma unroll
    for (int u = 0; u < 2; ++u)
      gload4(vt + 4096 + u * 256 + l * 4, vl + 4096 + u * 256);
  };

  // prologue: tile p -> buf0 (syncthreads drains vmcnt)
  stage(p, 0);
  __syncthreads();

  for (int n = 0; n < ntiles; ++n) {
    const int jt = p + 4 * n;
    const int cur = n & 1;
    if (n + 1 < ntiles) stage(jt + 4, cur ^ 1);  // DMA in flight over compute

    if (jt <= jtmaxW) {
      const int j0 = jt * 32;
      const short8* kb8 =
          reinterpret_cast<const short8*>(smem + (cur ? KOFF1 : KOFF0));
      const short* vt =
          reinterpret_cast<const short*>(smem + (cur ? VOFF1 : VOFF0));
      // ---- S = Q K^T (two 16-wide j sub-tiles) ----
      f32x4 sa0 = {0.f, 0.f, 0.f, 0.f}, sa1 = {0.f, 0.f, 0.f, 0.f};
#pragma unroll
      for (int c = 0; c < 8; ++c) {
        int row0 = c16, row1 = 16 + c16;
        int slot = 4 * c + g;
        short8 kf0 = kb8[row0 * 32 + (slot ^ (row0 & 7))];
        short8 kf1 = kb8[row1 * 32 + (slot ^ (row1 & 7))];
        sa0 = __builtin_amdgcn_mfma_f32_16x16x32_bf16(qf[c], kf0, sa0, 0, 0, 0);
        sa1 = __builtin_amdgcn_mfma_f32_16x16x32_bf16(qf[c], kf1, sa1, 0, 0, 0);
      }
      // ---- weights, causal mask, rowsum, P -> wave-private LDS ----
      float a0 = agb[j0 + c16];
      float a1 = agb[j0 + 16 + c16];
#pragma unroll
      for (int r = 0; r < 4; ++r) {
        int i = iw + 4 * g + r;
        float w0 = sa0[r] * 0.0625f * __expf(a0 - Mr[r]);
        if (j0 + c16 > i) w0 = 0.f;
        float w1 = sa1[r] * 0.0625f * __expf(a1 - Mr[r]);
        if (j0 + 16 + c16 > i) w1 = 0.f;
        rs[r] += w0 + w1;
        pb[(4 * g + r) * 40 + c16]      = f2bf(w0);
        pb[(4 * g + r) * 40 + 16 + c16] = f2bf(w1);
      }
      asm volatile("" ::: "memory");
      short8 pa = *reinterpret_cast<const short8*>(pb + c16 * 40 + 8 * g);
      // ---- O += P V ----
#pragma unroll
      for (int dq = 0; dq < 16; ++dq) {
        short8 vf = *reinterpret_cast<const short8*>(
            vt + (16 * dq + c16) * VSTR + 8 * (g ^ (dq & 3)));
        oa[dq] = __builtin_amdgcn_mfma_f32_16x16x32_bf16(pa, vf, oa[dq], 0, 0, 0);
      }
    }
    __syncthreads();  // drains vmcnt (next tile landed) + all LDS reads done
  }

  // ---- waves that never computed contribute nothing (outacc pre-zeroed) ----
  if (jtmaxW < p) return;

  // ---- rowsum reduce across the 16-lane group, then atomic accumulate ----
#pragma unroll
  for (int r = 0; r < 4; ++r) {
    rs[r] += __shfl_xor(rs[r], 1);
    rs[r] += __shfl_xor(rs[r], 2);
    rs[r] += __shfl_xor(rs[r], 4);
    rs[r] += __shfl_xor(rs[r], 8);
  }
  if (c16 == 0) {
#pragma unroll
    for (int r = 0; r < 4; ++r)
      atomicAdd(&rsb[hd * S_ + iw + 4 * g + r], rs[r]);
  }
#pragma unroll
  for (int dq = 0; dq < 16; ++dq)
#pragma unroll
    for (int r = 0; r < 4; ++r)
      atomicAdd(&outacc[((size_t)b * S_ + iw + 4 * g + r) * H_ + nh * DH_ +
                        dq * 16 + c16],
                oa[dq][r]);
}

// ---------------------------------------------------------------------------
// Kernel 4: in-place combine on d_out: normalizer + multihead layernorm.
// ---------------------------------------------------------------------------
__global__ __launch_bounds__(256) void combine_kernel(
    const float* __restrict__ rsb, const float* __restrict__ fl_arr,
    const float* __restrict__ scale, float* __restrict__ out) {
  int ridx = blockIdx.x * 4 + (threadIdx.x >> 6);
  int lane = threadIdx.x & 63;
  int hd = ridx >> 11, i = ridx & 2047;
  int b = hd >> 2, nh = hd & 3;

  float* op = out + ((size_t)b * S_ + i) * H_ + nh * DH_ + lane * 4;
  float4 a4 = *reinterpret_cast<const float4*>(op);

  float rsum = rsb[hd * S_ + i];
  float fl = fl_arr[(size_t)hd * S_ + i];
  float inv = 1.f / (fmaxf(fabsf(rsum), fl) + 1e-6f);

  float o0 = a4.x * inv;
  float o1 = a4.y * inv;
  float o2 = a4.z * inv;
  float o3 = a4.w * inv;

  float s1 = o0 + o1 + o2 + o3;
  float s2 = o0 * o0 + o1 * o1 + o2 * o2 + o3 * o3;
#pragma unroll
  for (int m = 1; m < 64; m <<= 1) {
    s1 += __shfl_xor(s1, m);
    s2 += __shfl_xor(s2, m);
  }
  float mean = s1 * (1.f / DH_);
  float var = s2 * (1.f / DH_) - mean * mean;
  float rstd = rsqrtf(var + 1e-6f);

  const float* scp = scale + nh * DH_ + lane * 4;
  float4 res;
  res.x = (o0 - mean) * rstd * scp[0];
  res.y = (o1 - mean) * rstd * scp[1];
  res.z = (o2 - mean) * rstd * scp[2];
  res.w = (o3 - mean) * rstd * scp[3];
  *reinterpret_cast<float4*>(op) = res;
}

// ---------------------------------------------------------------------------
extern "C" void kernel_launch(void* const* d_in, const int* in_sizes, int n_in,
                              void* d_out, int out_size, void* d_ws,
                              size_t ws_size, hipStream_t stream) {
  const float* q   = (const float*)d_in[0];
  const float* k   = (const float*)d_in[1];
  const float* v   = (const float*)d_in[2];
  const float* igk = (const float*)d_in[3];
  const float* igb = (const float*)d_in[4];
  const float* fgk = (const float*)d_in[5];
  const float* fgb = (const float*)d_in[6];
  const float* scl = (const float*)d_in[7];
  float* out = (float*)d_out;

  const size_t seq = (size_t)B_ * NH_ * S_;  // 16384
  float* ws = (float*)d_ws;
  float* ig_pre = ws;
  float* lsf    = ws + seq;
  float* a_arr  = ws + 2 * seq;
  float* M_arr  = ws + 3 * seq;
  float* fl_arr = ws + 4 * seq;
  float* rsb    = ws + 5 * seq;
  char*  kpack  = (char*)(ws + 6 * seq);                 // 8 MB
  char*  vpack  = kpack + (size_t)8 * 64 * KTILE_BYTES;  // 9.4 MB

  hipMemsetAsync(out, 0, (size_t)out_size * 4, stream);
  hipMemsetAsync(rsb, 0, seq * 4, stream);
  gates_kernel<<<B_ * S_, 256, 0, stream>>>(q, k, v, igk, igb, fgk, fgb,
                                            ig_pre, lsf);
  scan_kernel<<<B_ * NH_, 64, 0, stream>>>(ig_pre, lsf, a_arr, M_arr, fl_arr);
  pack_kv<<<8 * 64, 256, 0, stream>>>(k, v, kpack, vpack);
  mlstm_mfma<<<1024, 256, 0, stream>>>(q, a_arr, M_arr, kpack, vpack,
                                       out, rsb);
  combine_kernel<<<B_ * NH_ * S_ / 4, 256, 0, stream>>>(
      rsb, fl_arr, scl, out);
}

// Round 12
// 174.231 us; speedup vs baseline: 2.3135x; 1.2150x over previous
//
#include <hip/hip_runtime.h>
#include <hip/hip_bf16.h>
#include <math.h>

#define B_  2
#define S_  2048
#define H_  1024
#define NH_ 4
#define DH_ 256

typedef __attribute__((ext_vector_type(8))) short short8;
typedef __attribute__((ext_vector_type(4))) short short4v;
typedef __attribute__((ext_vector_type(2))) short short2v;
typedef __attribute__((ext_vector_type(4))) float f32x4;

#define KTILE_BYTES 16384   // 32 rows x 256 d x 2B (swizzled slots)
#define VTILE_BYTES 18432   // 256 d x 36 shorts (transposed, swizzled, padded)

static __device__ __forceinline__ short f2bf(float x) {
  __hip_bfloat16 h = __float2bfloat16(x);
  union { __hip_bfloat16 h; short s; } u;
  u.h = h;
  return u.s;
}

static __device__ __forceinline__ short8 pack8(const float4& a, const float4& b) {
  short8 t;
  t[0] = f2bf(a.x); t[1] = f2bf(a.y); t[2] = f2bf(a.z); t[3] = f2bf(a.w);
  t[4] = f2bf(b.x); t[5] = f2bf(b.y); t[6] = f2bf(b.z); t[7] = f2bf(b.w);
  return t;
}

// global -> LDS DMA. LDS dest is wave-uniform; HW adds lane*size.
static __device__ __forceinline__ void gload16(const void* g, void* l) {
  __builtin_amdgcn_global_load_lds(
      (const __attribute__((address_space(1))) unsigned int*)g,
      (__attribute__((address_space(3))) unsigned int*)l, 16, 0, 0);
}
static __device__ __forceinline__ void gload4(const void* g, void* l) {
  __builtin_amdgcn_global_load_lds(
      (const __attribute__((address_space(1))) unsigned int*)g,
      (__attribute__((address_space(3))) unsigned int*)l, 4, 0, 0);
}

// ---------------------------------------------------------------------------
// Kernel 1: gate projections (float4 h-vectorized, proven rounds 8-11).
// ---------------------------------------------------------------------------
__global__ __launch_bounds__(256) void gates_kernel(
    const float* __restrict__ q, const float* __restrict__ k,
    const float* __restrict__ v,
    const float* __restrict__ igk, const float* __restrict__ igb,
    const float* __restrict__ fgk, const float* __restrict__ fgb,
    float* __restrict__ ig_pre, float* __restrict__ lsf) {
  int bs = blockIdx.x;
  int b = bs / S_, s = bs % S_;
  const float* qrow = q + ((size_t)b * S_ + s) * H_;
  const float* krow = k + ((size_t)b * S_ + s) * H_;
  const float* vrow = v + ((size_t)b * S_ + s) * H_;

  int h0 = threadIdx.x * 4;
  float4 q4 = *reinterpret_cast<const float4*>(qrow + h0);
  float4 k4 = *reinterpret_cast<const float4*>(krow + h0);
  float4 v4 = *reinterpret_cast<const float4*>(vrow + h0);
  float qv[4] = {q4.x, q4.y, q4.z, q4.w};
  float kv[4] = {k4.x, k4.y, k4.z, k4.w};
  float vv[4] = {v4.x, v4.y, v4.z, v4.w};

  const float4* igk4 = reinterpret_cast<const float4*>(igk);
  const float4* fgk4 = reinterpret_cast<const float4*>(fgk);

  float accI[NH_] = {0.f, 0.f, 0.f, 0.f};
  float accF[NH_] = {0.f, 0.f, 0.f, 0.f};
#pragma unroll
  for (int e = 0; e < 4; ++e) {
    int h = h0 + e;
    float4 wiq = igk4[h], wik = igk4[H_ + h], wiv = igk4[2 * H_ + h];
    float4 wfq = fgk4[h], wfk = fgk4[H_ + h], wfv = fgk4[2 * H_ + h];
    accI[0] += qv[e] * wiq.x + kv[e] * wik.x + vv[e] * wiv.x;
    accI[1] += qv[e] * wiq.y + kv[e] * wik.y + vv[e] * wiv.y;
    accI[2] += qv[e] * wiq.z + kv[e] * wik.z + vv[e] * wiv.z;
    accI[3] += qv[e] * wiq.w + kv[e] * wik.w + vv[e] * wiv.w;
    accF[0] += qv[e] * wfq.x + kv[e] * wfk.x + vv[e] * wfv.x;
    accF[1] += qv[e] * wfq.y + kv[e] * wfk.y + vv[e] * wfv.y;
    accF[2] += qv[e] * wfq.z + kv[e] * wfk.z + vv[e] * wfv.z;
    accF[3] += qv[e] * wfq.w + kv[e] * wfk.w + vv[e] * wfv.w;
  }
#pragma unroll
  for (int n = 0; n < NH_; ++n) {
    for (int m = 1; m < 64; m <<= 1) {
      accI[n] += __shfl_xor(accI[n], m);
      accF[n] += __shfl_xor(accF[n], m);
    }
  }
  __shared__ float red[4][8];
  int wave = threadIdx.x >> 6;
  int lane = threadIdx.x & 63;
  if (lane == 0) {
#pragma unroll
    for (int n = 0; n < NH_; ++n) {
      red[wave][n] = accI[n];
      red[wave][4 + n] = accF[n];
    }
  }
  __syncthreads();
  if (threadIdx.x < 8) {
    int t = threadIdx.x;
    float sum = red[0][t] + red[1][t] + red[2][t] + red[3][t];
    if (t < 4) {
      int n = t;
      ig_pre[((size_t)(b * NH_ + n)) * S_ + s] = sum + igb[n];
    } else {
      int n = t - 4;
      float x = sum + fgb[n];
      float ls = (x >= 0.f) ? -log1pf(expf(-x)) : (x - log1pf(expf(x)));
      lsf[((size_t)(b * NH_ + n)) * S_ + s] = ls;
    }
  }
}

// ---------------------------------------------------------------------------
// Kernel 2: per-(b,nh) scan — in-register (proven rounds 6-11).
// ---------------------------------------------------------------------------
__global__ __launch_bounds__(64) void scan_kernel(
    const float* __restrict__ ig_pre, const float* __restrict__ lsf,
    float* __restrict__ a_out, float* __restrict__ M_out,
    float* __restrict__ fl_out) {
  int hd = blockIdx.x;
  int lane = threadIdx.x;
  const float* ig = ig_pre + (size_t)hd * S_;
  const float* ls = lsf + (size_t)hd * S_;
  float xs[32], ys[32];
#pragma unroll
  for (int c = 0; c < 32; ++c) xs[c] = ls[c * 64 + lane];
#pragma unroll
  for (int c = 0; c < 32; ++c) ys[c] = ig[c * 64 + lane];

  float carry = 0.f;
  float mcarry = -INFINITY;
#pragma unroll
  for (int c = 0; c < 32; ++c) {
    int s = c * 64 + lane;
    float x = xs[c];
    for (int off = 1; off < 64; off <<= 1) {
      float t = __shfl_up(x, off);
      if (lane >= off) x += t;
    }
    float csum = carry + x;
    float a = ys[c] - csum;
    float y = a;
    for (int off = 1; off < 64; off <<= 1) {
      float t = __shfl_up(y, off);
      if (lane >= off) y = fmaxf(y, t);
    }
    float M = fmaxf(mcarry, y);
    a_out[(size_t)hd * S_ + s] = a;
    M_out[(size_t)hd * S_ + s] = M;
    fl_out[(size_t)hd * S_ + s] = expf(-(csum + M));
    carry = __shfl(csum, 63);
    mcarry = __shfl(M, 63);
  }
}

// ---------------------------------------------------------------------------
// Kernel 2b: pack K and V tiles to bf16 global images in byte-exact LDS
// layouts (swizzles baked in) — proven round 11.
// ---------------------------------------------------------------------------
__global__ __launch_bounds__(256) void pack_kv(
    const float* __restrict__ k, const float* __restrict__ v,
    char* __restrict__ kpack, char* __restrict__ vpack) {
  const int bidx = blockIdx.x;
  const int hd = bidx & 7, jt = bidx >> 3;
  const int b = hd >> 2, nh = hd & 3;
  const float* kgb = k + ((size_t)b * S_ + jt * 32) * H_ + nh * DH_;
  const float* vgb = v + ((size_t)b * S_ + jt * 32) * H_ + nh * DH_;
  char* kp = kpack + ((size_t)(hd * 64 + jt)) * KTILE_BYTES;
  char* vp = vpack + ((size_t)(hd * 64 + jt)) * VTILE_BYTES;
  const int tid = threadIdx.x;

  {
    int j = tid >> 3, sck = tid & 7;
    const float* row = kgb + (size_t)j * H_ + sck * 32;
    short8* out8 = reinterpret_cast<short8*>(kp) + j * 32;
#pragma unroll
    for (int u = 0; u < 4; ++u) {
      float4 a0 = *reinterpret_cast<const float4*>(row + 8 * u);
      float4 a1 = *reinterpret_cast<const float4*>(row + 8 * u + 4);
      out8[(4 * sck + u) ^ (j & 7)] = pack8(a0, a1);
    }
  }
  {
    int d = tid;
    int jsw = ((d >> 4) & 3) << 3;
    short4v* dst = reinterpret_cast<short4v*>(vp + (size_t)d * 72);
#pragma unroll
    for (int c = 0; c < 8; ++c) {
      short4v t;
#pragma unroll
      for (int e = 0; e < 4; ++e)
        t[e] = f2bf(vgb[(size_t)((4 * c + e) ^ jsw) * H_ + d]);
      dst[c] = t;
    }
    short4v z = {0, 0, 0, 0};
    dst[8] = z;
  }
}

// ---------------------------------------------------------------------------
// Kernel 3: MFMA main. 2-way parity split, plain-store partials (NO atomics).
//   grid 512: p=bid>>8, idx=bid&255, hd=idx&7 (XCD-affine), cs=idx>>3,
//   rtb=(p)?cs:31-cs (complement pairing: CU pair works (32-cs)+(cs+1)=33).
//   Block does tiles jt=p, p+2, ... (ntiles = rtb+1 <= 32).
//   p=0 partial O -> d_out (plain f32 store), p=1 -> po1. Rowsums -> rsA/rsB.
//   Every block fully overwrites its rows (zeros incl.) -> NO memset needed.
// LDS (double-buffered K and V, DMA-written; proven round 11):
//   K0 [0,16384) K1 [16384,32768) V0 [32768,51200) V1 [51200,69632)
//   P  [69632,74752) per-wave [16][40] shorts.  2 blocks/CU: 149.5KB <= 160KB.
// ---------------------------------------------------------------------------
#define KOFF0 0
#define KOFF1 16384
#define VOFF0 32768
#define VOFF1 51200
#define POFF  69632
#define SMEM_BYTES (POFF + 4 * 1280)
#define VSTR 36

__global__ __launch_bounds__(256, 2) void mlstm_mfma(
    const float* __restrict__ q,
    const float* __restrict__ a_arr, const float* __restrict__ M_arr,
    const char* __restrict__ kpack, const char* __restrict__ vpack,
    float* __restrict__ outacc, float* __restrict__ po1,
    float* __restrict__ rsA, float* __restrict__ rsB) {
  __shared__ __align__(16) char smem[SMEM_BYTES];

  const int bid = blockIdx.x;
  const int p = bid >> 8;
  const int idx = bid & 255;
  const int hd = idx & 7;
  const int cs = idx >> 3;
  const int rtb = p ? cs : 31 - cs;
  const int ntiles = rtb + 1;

  const int b = hd >> 2, nh = hd & 3;
  const int i0 = rtb * 64;

  const int tid = threadIdx.x;
  const int wave = tid >> 6;
  const int l = tid & 63;
  const int g = l >> 4;      // 0..3
  const int c16 = l & 15;    // 0..15
  const int iw = i0 + wave * 16;

  short* pb = reinterpret_cast<short*>(smem + POFF + wave * 1280);
  const char* ktiles = kpack + (size_t)hd * 64 * KTILE_BYTES;
  const char* vtiles = vpack + (size_t)hd * 64 * VTILE_BYTES;

  // ---- Q A-fragments: row = iw + c16, k-elems = 32c + 8g + e ----
  short8 qf[8];
  {
    const float* qp = q + ((size_t)b * S_ + (iw + c16)) * H_ + nh * DH_;
#pragma unroll
    for (int c = 0; c < 8; ++c) {
      int d0 = c * 32 + g * 8;
      float4 f0 = *reinterpret_cast<const float4*>(qp + d0);
      float4 f1 = *reinterpret_cast<const float4*>(qp + d0 + 4);
      qf[c] = pack8(f0, f1);
    }
  }
  float Mr[4];
#pragma unroll
  for (int r = 0; r < 4; ++r)
    Mr[r] = M_arr[(size_t)hd * S_ + iw + 4 * g + r];

  f32x4 oa[16];
#pragma unroll
  for (int d = 0; d < 16; ++d) oa[d] = (f32x4){0.f, 0.f, 0.f, 0.f};
  float rs[4] = {0.f, 0.f, 0.f, 0.f};

  const float* agb = a_arr + (size_t)hd * S_;
  const int jtmaxW = (iw + 15) >> 5;  // causal cap per wave

  // DMA stage: 4x16B K + 4x16B V + 2x4B V tail per wave (wave-uniform dest)
  auto stage = [&](int jt, int buf) {
    const char* kt = ktiles + (size_t)jt * KTILE_BYTES + wave * 4096;
    char* kl = smem + (buf ? KOFF1 : KOFF0) + wave * 4096;
#pragma unroll
    for (int u = 0; u < 4; ++u)
      gload16(kt + u * 1024 + l * 16, kl + u * 1024);
    const char* vt = vtiles + (size_t)jt * VTILE_BYTES + wave * 4608;
    char* vl = smem + (buf ? VOFF1 : VOFF0) + wave * 4608;
#pragma unroll
    for (int u = 0; u < 4; ++u)
      gload16(vt + u * 1024 + l * 16, vl + u * 1024);
#pragma unroll
    for (int u = 0; u < 2; ++u)
      gload4(vt + 4096 + u * 256 + l * 4, vl + 4096 + u * 256);
  };

  // prologue: tile p -> buf0 (syncthreads drains vmcnt)
  stage(p, 0);
  __syncthreads();

  for (int n = 0; n < ntiles; ++n) {
    const int jt = p + 2 * n;
    const int cur = n & 1;
    if (n + 1 < ntiles) stage(jt + 2, cur ^ 1);  // DMA in flight over compute

    if (jt <= jtmaxW) {
      const int j0 = jt * 32;
      const short8* kb8 =
          reinterpret_cast<const short8*>(smem + (cur ? KOFF1 : KOFF0));
      const short* vt =
          reinterpret_cast<const short*>(smem + (cur ? VOFF1 : VOFF0));
      // ---- S = Q K^T (two 16-wide j sub-tiles) ----
      f32x4 sa0 = {0.f, 0.f, 0.f, 0.f}, sa1 = {0.f, 0.f, 0.f, 0.f};
#pragma unroll
      for (int c = 0; c < 8; ++c) {
        int row0 = c16, row1 = 16 + c16;
        int slot = 4 * c + g;
        short8 kf0 = kb8[row0 * 32 + (slot ^ (row0 & 7))];
        short8 kf1 = kb8[row1 * 32 + (slot ^ (row1 & 7))];
        sa0 = __builtin_amdgcn_mfma_f32_16x16x32_bf16(qf[c], kf0, sa0, 0, 0, 0);
        sa1 = __builtin_amdgcn_mfma_f32_16x16x32_bf16(qf[c], kf1, sa1, 0, 0, 0);
      }
      // ---- weights, causal mask, rowsum, P -> wave-private LDS ----
      float a0 = agb[j0 + c16];
      float a1 = agb[j0 + 16 + c16];
#pragma unroll
      for (int r = 0; r < 4; ++r) {
        int i = iw + 4 * g + r;
        float w0 = sa0[r] * 0.0625f * __expf(a0 - Mr[r]);
        if (j0 + c16 > i) w0 = 0.f;
        float w1 = sa1[r] * 0.0625f * __expf(a1 - Mr[r]);
        if (j0 + 16 + c16 > i) w1 = 0.f;
        rs[r] += w0 + w1;
        pb[(4 * g + r) * 40 + c16]      = f2bf(w0);
        pb[(4 * g + r) * 40 + 16 + c16] = f2bf(w1);
      }
      asm volatile("" ::: "memory");
      short8 pa = *reinterpret_cast<const short8*>(pb + c16 * 40 + 8 * g);
      // ---- O += P V ----
#pragma unroll
      for (int dq = 0; dq < 16; ++dq) {
        short8 vf = *reinterpret_cast<const short8*>(
            vt + (16 * dq + c16) * VSTR + 8 * (g ^ (dq & 3)));
        oa[dq] = __builtin_amdgcn_mfma_f32_16x16x32_bf16(pa, vf, oa[dq], 0, 0, 0);
      }
    }
    __syncthreads();  // drains vmcnt (next tile landed) + all LDS reads done
  }

  // ---- rowsum reduce across the 16-lane group ----
#pragma unroll
  for (int r = 0; r < 4; ++r) {
    rs[r] += __shfl_xor(rs[r], 1);
    rs[r] += __shfl_xor(rs[r], 2);
    rs[r] += __shfl_xor(rs[r], 4);
    rs[r] += __shfl_xor(rs[r], 8);
  }

  // ---- plain-store partials (no atomics; zero rows written too) ----
  float* rsP = p ? rsB : rsA;
  if (c16 == 0) {
#pragma unroll
    for (int r = 0; r < 4; ++r)
      rsP[hd * S_ + iw + 4 * g + r] = rs[r];
  }
  if (p == 0) {
#pragma unroll
    for (int dq = 0; dq < 16; ++dq)
#pragma unroll
      for (int r = 0; r < 4; ++r)
        outacc[((size_t)b * S_ + iw + 4 * g + r) * H_ + nh * DH_ +
               dq * 16 + c16] = oa[dq][r];
  } else {
#pragma unroll
    for (int dq = 0; dq < 16; ++dq)
#pragma unroll
      for (int r = 0; r < 4; ++r)
        po1[((size_t)(hd * S_ + iw + 4 * g + r)) * DH_ + dq * 16 + c16] =
            oa[dq][r];
  }
}

// ---------------------------------------------------------------------------
// Kernel 4: combine p0 (in d_out) + p1 (po1) -> normalizer + LN, in-place.
// ---------------------------------------------------------------------------
__global__ __launch_bounds__(256) void combine_kernel(
    const float* __restrict__ po1, const float* __restrict__ rsA,
    const float* __restrict__ rsB, const float* __restrict__ fl_arr,
    const float* __restrict__ scale, float* __restrict__ out) {
  int ridx = blockIdx.x * 4 + (threadIdx.x >> 6);
  int lane = threadIdx.x & 63;
  int hd = ridx >> 11, i = ridx & 2047;
  int b = hd >> 2, nh = hd & 3;

  float* op = out + ((size_t)b * S_ + i) * H_ + nh * DH_ + lane * 4;
  float4 a4 = *reinterpret_cast<const float4*>(op);
  float4 b4 = *reinterpret_cast<const float4*>(
      po1 + ((size_t)(hd * S_ + i)) * DH_ + lane * 4);

  float rsum = rsA[hd * S_ + i] + rsB[hd * S_ + i];
  float fl = fl_arr[(size_t)hd * S_ + i];
  float inv = 1.f / (fmaxf(fabsf(rsum), fl) + 1e-6f);

  float o0 = (a4.x + b4.x) * inv;
  float o1 = (a4.y + b4.y) * inv;
  float o2 = (a4.z + b4.z) * inv;
  float o3 = (a4.w + b4.w) * inv;

  float s1 = o0 + o1 + o2 + o3;
  float s2 = o0 * o0 + o1 * o1 + o2 * o2 + o3 * o3;
#pragma unroll
  for (int m = 1; m < 64; m <<= 1) {
    s1 += __shfl_xor(s1, m);
    s2 += __shfl_xor(s2, m);
  }
  float mean = s1 * (1.f / DH_);
  float var = s2 * (1.f / DH_) - mean * mean;
  float rstd = rsqrtf(var + 1e-6f);

  const float* scp = scale + nh * DH_ + lane * 4;
  float4 res;
  res.x = (o0 - mean) * rstd * scp[0];
  res.y = (o1 - mean) * rstd * scp[1];
  res.z = (o2 - mean) * rstd * scp[2];
  res.w = (o3 - mean) * rstd * scp[3];
  *reinterpret_cast<float4*>(op) = res;
}

// ---------------------------------------------------------------------------
extern "C" void kernel_launch(void* const* d_in, const int* in_sizes, int n_in,
                              void* d_out, int out_size, void* d_ws,
                              size_t ws_size, hipStream_t stream) {
  const float* q   = (const float*)d_in[0];
  const float* k   = (const float*)d_in[1];
  const float* v   = (const float*)d_in[2];
  const float* igk = (const float*)d_in[3];
  const float* igb = (const float*)d_in[4];
  const float* fgk = (const float*)d_in[5];
  const float* fgb = (const float*)d_in[6];
  const float* scl = (const float*)d_in[7];
  float* out = (float*)d_out;

  const size_t seq = (size_t)B_ * NH_ * S_;  // 16384
  float* ws = (float*)d_ws;
  float* ig_pre = ws;
  float* lsf    = ws + seq;
  float* a_arr  = ws + 2 * seq;
  float* M_arr  = ws + 3 * seq;
  float* fl_arr = ws + 4 * seq;
  float* rsA    = ws + 5 * seq;
  float* rsB    = ws + 6 * seq;
  char*  kpack  = (char*)(ws + 7 * seq);                 // 8 MB
  char*  vpack  = kpack + (size_t)8 * 64 * KTILE_BYTES;  // 9.4 MB
  float* po1    = (float*)(vpack + (size_t)8 * 64 * VTILE_BYTES);  // 16.8 MB

  gates_kernel<<<B_ * S_, 256, 0, stream>>>(q, k, v, igk, igb, fgk, fgb,
                                            ig_pre, lsf);
  scan_kernel<<<B_ * NH_, 64, 0, stream>>>(ig_pre, lsf, a_arr, M_arr, fl_arr);
  pack_kv<<<8 * 64, 256, 0, stream>>>(k, v, kpack, vpack);
  mlstm_mfma<<<512, 256, 0, stream>>>(q, a_arr, M_arr, kpack, vpack,
                                      out, po1, rsA, rsB);
  combine_kernel<<<B_ * NH_ * S_ / 4, 256, 0, stream>>>(
      po1, rsA, rsB, fl_arr, scl, out);
}